// Round 10
// baseline (319.729 us; speedup 1.0000x reference)
//
#include <hip/hip_runtime.h>
#include <math.h>

#define BB 2
#define TT 1024
#define DD 1024
#define HH 16
#define HS 64
#define NROWS (BB*TT)   // 2048

typedef _Float16 f16;
typedef __attribute__((ext_vector_type(8))) _Float16 half8;
typedef __attribute__((ext_vector_type(4))) _Float16 half4;
typedef __attribute__((ext_vector_type(4))) float f32x4;

constexpr float EPS   = 1e-5f;
constexpr float SCALE = 8.0f;   // faithful bug: scores * sqrt(HS)

__device__ __forceinline__ void load_lds16(const f16* g, f16* l) {
    __builtin_amdgcn_global_load_lds(
        (const __attribute__((address_space(1))) unsigned int*)g,
        (__attribute__((address_space(3))) unsigned int*)l, 16, 0, 0);
}

// XCD-aware bijective swizzle of the linear block id (total % 8 == 0).
__device__ __forceinline__ int xcd_swizzle(int lin, int total) {
    if ((total & 7) == 0) {
        const int chunk = total >> 3;
        lin = (lin & 7) * chunk + (lin >> 3);
    }
    return lin;
}

// ---------------- dual RMSNorm: rows 0..2047 = src -> xn_s, 2048..4095 = att -> xn_a
__global__ __launch_bounds__(256) void rms2_kernel(const float* __restrict__ src,
                                                   const float* __restrict__ att,
                                                   const float* __restrict__ w,
                                                   f16* __restrict__ xn_s,
                                                   f16* __restrict__ xn_a) {
    const int bid = blockIdx.x;
    const int tid = threadIdx.x;
    const int row = bid & (NROWS - 1);
    const float* xr = ((bid < NROWS) ? src : att) + (size_t)row * DD;
    f16* out = ((bid < NROWS) ? xn_s : xn_a) + (size_t)row * DD;

    float4 xv = reinterpret_cast<const float4*>(xr)[tid];
    float ss = xv.x*xv.x + xv.y*xv.y + xv.z*xv.z + xv.w*xv.w;

    __shared__ float red[256];
    red[tid] = ss; __syncthreads();
    for (int s = 128; s > 0; s >>= 1) {
        if (tid < s) red[tid] += red[tid + s];
        __syncthreads();
    }
    const float inv = rsqrtf(red[0] * (1.0f / DD) + EPS);

    float4 wv = reinterpret_cast<const float4*>(w)[tid];
    half4 o;
    o.x = (f16)(xv.x * inv * wv.x);
    o.y = (f16)(xv.y * inv * wv.y);
    o.z = (f16)(xv.z * inv * wv.z);
    o.w = (f16)(xv.w * inv * wv.w);
    *reinterpret_cast<half4*>(&out[tid * 4]) = o;
}

// ---------------- fused weight prep: all 10 transposes + 5120-bias pack ----------
// wt layout (f16, units of M_=1M): [0:3 qkv_m][3 wq_f][4 wk_f][5 wv_f][6 projm]
//                                  [7 projf][8:12 w1][12:16 w2]
__global__ __launch_bounds__(256) void wtrans_all(
    const float* __restrict__ wq_m, const float* __restrict__ wk_m,
    const float* __restrict__ wv_m, const float* __restrict__ proj_m_w,
    const float* __restrict__ wq_f, const float* __restrict__ wk_f,
    const float* __restrict__ wv_f, const float* __restrict__ proj_f_w,
    const float* __restrict__ w1,   const float* __restrict__ w2,
    f16* __restrict__ wt,
    const float* __restrict__ bq, const float* __restrict__ bk,
    float* __restrict__ biascat)
{
    const int bid = blockIdx.x;
    const int tid = threadIdx.x;
    const size_t M_ = 1024 * 1024;

    if (bid >= 4096) {   // bias pack: [0]*3072 | bq | bk  (5120 floats)
        for (int j = tid; j < 5120; j += 256)
            biascat[j] = (j < 3072) ? 0.f : ((j < 4096) ? bq[j - 3072] : bk[j - 4096]);
        return;
    }

    const float* W; f16* Wt; int K, N, lognk, t; bool headw;
    if (bid < 768)       { const int m = bid >> 8;
                           W = (m == 0) ? wq_m : (m == 1) ? wk_m : wv_m;
                           Wt = wt + (size_t)m * M_;
                           K = 1024; N = 1024; lognk = 4; headw = true;  t = bid & 255; }
    else if (bid < 1024) { W = proj_m_w; Wt = wt + 6 * M_;
                           K = 1024; N = 1024; lognk = 4; headw = false; t = bid - 768; }
    else if (bid < 1792) { const int m = (bid - 1024) >> 8;
                           W = (m == 0) ? wq_f : (m == 1) ? wk_f : wv_f;
                           Wt = wt + (size_t)(3 + m) * M_;
                           K = 1024; N = 1024; lognk = 4; headw = true;  t = (bid - 1024) & 255; }
    else if (bid < 2048) { W = proj_f_w; Wt = wt + 7 * M_;
                           K = 1024; N = 1024; lognk = 4; headw = false; t = bid - 1792; }
    else if (bid < 3072) { W = w1; Wt = wt + 8 * M_;
                           K = 1024; N = 4096; lognk = 4; headw = false; t = bid - 2048; }
    else                 { W = w2; Wt = wt + 12 * M_;
                           K = 4096; N = 1024; lognk = 6; headw = false; t = bid - 3072; }

    const int k0 = (t & ((1 << lognk) - 1)) * 64;
    const int n0 = (t >> lognk) * 64;

    __shared__ float tt[64][65];
    #pragma unroll
    for (int r = 0; r < 4; ++r) {
        const int idx = tid + r * 256;
        const int kl  = idx >> 4;
        const int nl4 = (idx & 15) * 4;
        const float* gp;
        if (headw) {
            gp = W + ((size_t)(n0 >> 6) * K + (k0 + kl)) * 64 + nl4;
        } else {
            gp = W + (size_t)(k0 + kl) * N + n0 + nl4;
        }
        float4 v = *reinterpret_cast<const float4*>(gp);
        tt[kl][nl4 + 0] = v.x; tt[kl][nl4 + 1] = v.y;
        tt[kl][nl4 + 2] = v.z; tt[kl][nl4 + 3] = v.w;
    }
    __syncthreads();
    #pragma unroll
    for (int r = 0; r < 4; ++r) {
        const int idx = tid + r * 256;
        const int nl  = idx >> 4;
        const int kl4 = (idx & 15) * 4;
        half4 o;
        o.x = (f16)tt[kl4 + 0][nl];
        o.y = (f16)tt[kl4 + 1][nl];
        o.z = (f16)tt[kl4 + 2][nl];
        o.w = (f16)tt[kl4 + 3][nl];
        *reinterpret_cast<half4*>(&Wt[(size_t)(n0 + nl) * K + k0 + kl4]) = o;
    }
}

// ---------------- fp16 MFMA GEMM, BM x 128 tiles, templated BK, 2-buffer --------
// BK=64: 8 global_load_lds/thread in flight per step, 32 MFMA/wave/step, half the
// barriers of BK=32 -> latency per step amortized over 2x compute.
// Column-major block walk under the XCD swizzle (B panel L2-resident per XCD).
// grid (N/128, M/BM, ksplit). PARTIAL: z writes f16 partials to outH + z*M*N.
// HEADOUT: col -> mat = col>>10, out = outH + mat*2M + head-layout index.
template<int BM, int BK, int EPI, bool HEADOUT, bool SPLITA, bool OHALF, bool PARTIAL>
__global__ __launch_bounds__(256, 2) void gemm_mfma(
    const f16* __restrict__ A1,
    const f16* __restrict__ A2,
    const f16* __restrict__ Bt,
    const float* __restrict__ bias,
    float* __restrict__ outF,
    f16* __restrict__ outH,
    int N, int K, int splitN)
{
    constexpr int MI = 4;
    constexpr int NI = (BM == 128) ? 4 : 2;
    constexpr int WN = (BM == 128) ? 64 : 32;
    constexpr int KH = BK / 8;                // 8-f16 k-chunks per K-step
    constexpr int ASLOT = BM * KH;            // 16B slots per A tile
    constexpr int BSLOT = 128 * KH;
    constexpr int AINST = ASLOT / 256;
    constexpr int BINST = BSLOT / 256;
    constexpr int KS = BK / 32;               // MFMA k-subloops

    __shared__ f16 ldsA[2][ASLOT * 8];
    __shared__ f16 ldsB[2][BSLOT * 8];

    const int tid  = threadIdx.x;
    const int lane = tid & 63;
    const int wid  = tid >> 6;
    const int gy = gridDim.y;
    const int lin = xcd_swizzle(blockIdx.y * gridDim.x + blockIdx.x,
                                gridDim.x * gy);
    const int m0 = (lin % gy) * BM;
    const int n0 = (lin / gy) * 128;
    const int wm = (BM == 128) ? (wid >> 1) : 0;
    const int wn = (BM == 128) ? (wid & 1) : wid;

    const int Klen  = K / gridDim.z;
    const int kbase = blockIdx.z * Klen;

    const f16* Aptr = (SPLITA && n0 >= splitN) ? A2 : A1;

    f32x4 acc[MI][NI];
    #pragma unroll
    for (int i = 0; i < MI; ++i)
        #pragma unroll
        for (int j = 0; j < NI; ++j)
            acc[i][j] = (f32x4){0.f, 0.f, 0.f, 0.f};

    auto stage = [&](int buf, int kt) {
        const int k0 = kbase + kt * BK;
        #pragma unroll
        for (int i = 0; i < AINST; ++i) {
            const int s   = (wid * AINST + i) * 64 + lane;
            const int kh  = s / BM;
            const int row = s % BM;
            load_lds16(Aptr + (size_t)(m0 + row) * K + (k0 + kh * 8),
                       &ldsA[buf][s * 8]);
        }
        #pragma unroll
        for (int i = 0; i < BINST; ++i) {
            const int s   = (wid * BINST + i) * 64 + lane;
            const int kh  = s >> 7;
            const int col = s & 127;
            load_lds16(Bt + (size_t)(n0 + col) * K + (k0 + kh * 8),
                       &ldsB[buf][s * 8]);
        }
    };

    const int NT = Klen / BK;
    stage(0, 0);
    __syncthreads();
    int cur = 0;
    const int l15 = lane & 15, l4 = lane >> 4;
    for (int kt = 0; kt < NT; ++kt) {
        if (kt + 1 < NT) stage(cur ^ 1, kt + 1);
        #pragma unroll
        for (int ks = 0; ks < KS; ++ks) {
            half8 af[MI], bfr[NI];
            #pragma unroll
            for (int mi = 0; mi < MI; ++mi)
                af[mi] = *reinterpret_cast<const half8*>(
                    &ldsA[cur][((ks * 4 + l4) * BM + wm * 64 + mi * 16 + l15) * 8]);
            #pragma unroll
            for (int ni = 0; ni < NI; ++ni)
                bfr[ni] = *reinterpret_cast<const half8*>(
                    &ldsB[cur][((ks * 4 + l4) * 128 + wn * WN + ni * 16 + l15) * 8]);
            #pragma unroll
            for (int mi = 0; mi < MI; ++mi)
                #pragma unroll
                for (int ni = 0; ni < NI; ++ni)
                    acc[mi][ni] = __builtin_amdgcn_mfma_f32_16x16x32_f16(
                        af[mi], bfr[ni], acc[mi][ni], 0, 0, 0);
        }
        __syncthreads();
        cur ^= 1;
    }

    f16* pout = nullptr;
    if (PARTIAL) {
        const size_t MN = (size_t)gridDim.y * BM * N;
        pout = outH + (size_t)blockIdx.z * MN;
    }

    #pragma unroll
    for (int mi = 0; mi < MI; ++mi) {
        #pragma unroll
        for (int ni = 0; ni < NI; ++ni) {
            #pragma unroll
            for (int r = 0; r < 4; ++r) {
                const int row = m0 + wm * 64 + mi * 16 + l4 * 4 + r;
                const int col = n0 + wn * WN + ni * 16 + l15;
                float v = acc[mi][ni][r];
                if (PARTIAL) {
                    pout[(size_t)row * N + col] = (f16)v;
                    continue;
                }
                if (EPI >= 1) v += bias[col];
                if (EPI == 2) v = 0.5f * v * (1.0f + erff(v * 0.70710678118f));
                size_t oidx;
                if (HEADOUT) {
                    const int mat = col >> 10;
                    const int h = (col >> 6) & 15, e = col & 63;
                    const int b = row >> 10, t = row & (TT - 1);
                    oidx = (size_t)mat * ((size_t)NROWS * DD)
                         + ((size_t)((b * HH + h) * TT + t)) * HS + e;
                } else {
                    oidx = (size_t)row * N + col;
                }
                if (OHALF) outH[oidx] = (f16)v;
                else       outF[oidx] = v;
            }
        }
    }
}

// ---------------- split-K reduce epilogues (f16 partials), N=1024, 1 row/block --
// MODE 0: out_h = sum + bias + residF(src)                  [m_out f16]
// MODE 1: outF = sum + bias + residH(m_out); xn = rms(outF) [f_out + fused rmsnorm]
// MODE 2: outF = sum + bias + residF(f_out)                 [final output]
template<int MODE>
__global__ __launch_bounds__(256) void reduce_fuse(const f16* __restrict__ part,
                                                   const float* __restrict__ bias,
                                                   const float* __restrict__ residF,
                                                   const f16* __restrict__ residH,
                                                   float* __restrict__ outF,
                                                   f16* __restrict__ outH,
                                                   const float* __restrict__ normw,
                                                   f16* __restrict__ xnout) {
    const size_t MN  = (size_t)NROWS * 1024;
    const int tid = threadIdx.x;
    const size_t idx = ((size_t)blockIdx.x * 256 + tid) * 4;
    float o[4];
    {
        half4 p0 = *reinterpret_cast<const half4*>(part + idx);
        half4 p1 = *reinterpret_cast<const half4*>(part + MN + idx);
        half4 p2 = *reinterpret_cast<const half4*>(part + 2 * MN + idx);
        half4 p3 = *reinterpret_cast<const half4*>(part + 3 * MN + idx);
        float4 bi = *reinterpret_cast<const float4*>(bias + (idx & 1023));
        o[0] = (float)p0.x + (float)p1.x + (float)p2.x + (float)p3.x + bi.x;
        o[1] = (float)p0.y + (float)p1.y + (float)p2.y + (float)p3.y + bi.y;
        o[2] = (float)p0.z + (float)p1.z + (float)p2.z + (float)p3.z + bi.z;
        o[3] = (float)p0.w + (float)p1.w + (float)p2.w + (float)p3.w + bi.w;
    }
    if (MODE == 0 || MODE == 2) {
        float4 rs = *reinterpret_cast<const float4*>(residF + idx);
        o[0] += rs.x; o[1] += rs.y; o[2] += rs.z; o[3] += rs.w;
    } else {
        half4 rh = *reinterpret_cast<const half4*>(residH + idx);
        o[0] += (float)rh.x; o[1] += (float)rh.y; o[2] += (float)rh.z; o[3] += (float)rh.w;
    }

    if (MODE == 0) {
        half4 h;
        h.x = (f16)o[0]; h.y = (f16)o[1]; h.z = (f16)o[2]; h.w = (f16)o[3];
        *reinterpret_cast<half4*>(outH + idx) = h;
        return;
    }

    float4 ov = {o[0], o[1], o[2], o[3]};
    *reinterpret_cast<float4*>(outF + idx) = ov;

    if (MODE == 1) {   // fused rmsnorm of the row (block == one row of 1024)
        __shared__ float red[256];
        red[tid] = o[0]*o[0] + o[1]*o[1] + o[2]*o[2] + o[3]*o[3];
        __syncthreads();
        for (int s = 128; s > 0; s >>= 1) {
            if (tid < s) red[tid] += red[tid + s];
            __syncthreads();
        }
        const float inv = rsqrtf(red[0] * (1.0f / DD) + EPS);
        float4 nw = *reinterpret_cast<const float4*>(normw + (idx & 1023));
        half4 h;
        h.x = (f16)(o[0] * inv * nw.x);
        h.y = (f16)(o[1] * inv * nw.y);
        h.z = (f16)(o[2] * inv * nw.z);
        h.w = (f16)(o[3] * inv * nw.w);
        *reinterpret_cast<half4*>(xnout + idx) = h;
    }
}

// ---------------- MFMA flash attention (fp16 in/out, fp32 softmax/acc) ----------------
template<bool CAUSAL>
__global__ __launch_bounds__(256) void attn_mfma(const f16* __restrict__ Q,
                                                 const f16* __restrict__ Kg,
                                                 const f16* __restrict__ Vg,
                                                 f16* __restrict__ O) {
    const int iq  = blockIdx.x;
    const int bh  = blockIdx.y;
    const int tid = threadIdx.x;
    const int lane = tid & 63;
    const int w   = tid >> 6;
    const int l15 = lane & 15, l4 = lane >> 4;

    __shared__ f16 Ks[512 * 8];      // slot-major: slot = eh*64 + s
    __shared__ f16 VT[64 * 72];      // VT[e][s], row stride 72
    __shared__ f16 Ps[4][16 * 72];   // per-wave P[q'][s], row stride 72

    const f16* qb = Q  + ((size_t)bh * TT + (size_t)iq * 64) * HS;
    const f16* kb = Kg + (size_t)bh * TT * HS;
    const f16* vb = Vg + (size_t)bh * TT * HS;

    half8 qf[2];
    #pragma unroll
    for (int ks = 0; ks < 2; ++ks)
        qf[ks] = *reinterpret_cast<const half8*>(
            qb + (size_t)(w * 16 + l15) * HS + ks * 32 + l4 * 8);

    f32x4 oacc[4];
    #pragma unroll
    for (int ni = 0; ni < 4; ++ni) oacc[ni] = (f32x4){0.f, 0.f, 0.f, 0.f};
    float m_run[4], l_run[4];
    #pragma unroll
    for (int r = 0; r < 4; ++r) { m_run[r] = -1e30f; l_run[r] = 0.f; }

    const int sp  = lane & 31;
    const int ehv = lane >> 5;
    const int c0  = w * 16 + ehv * 8;

    const int ntiles = CAUSAL ? (iq + 1) : (TT / 64);
    for (int js = 0; js < ntiles; ++js) {
        __syncthreads();

        #pragma unroll
        for (int i = 0; i < 2; ++i) {
            const int slot = (w * 2 + i) * 64 + lane;
            load_lds16(kb + (size_t)(js * 64 + (slot & 63)) * HS + (slot >> 6) * 8,
                       &Ks[slot * 8]);
        }
        {
            const f16* vrow = vb + (size_t)(js * 64 + 2 * sp) * HS + c0;
            uint4 r0 = *reinterpret_cast<const uint4*>(vrow);
            uint4 r1 = *reinterpret_cast<const uint4*>(vrow + HS);
            const unsigned rc0[4] = {r0.x, r0.y, r0.z, r0.w};
            const unsigned rc1[4] = {r1.x, r1.y, r1.z, r1.w};
            #pragma unroll
            for (int i = 0; i < 8; ++i) {
                const unsigned lo = (i & 1) ? (rc0[i >> 1] >> 16) : (rc0[i >> 1] & 0xffffu);
                const unsigned hi = (i & 1) ? (rc1[i >> 1] >> 16) : (rc1[i >> 1] & 0xffffu);
                *reinterpret_cast<unsigned*>(&VT[(c0 + i) * 72 + 2 * sp]) = lo | (hi << 16);
            }
        }
        __syncthreads();

        f32x4 sacc[4];
        #pragma unroll
        for (int ni = 0; ni < 4; ++ni) sacc[ni] = (f32x4){0.f, 0.f, 0.f, 0.f};
        #pragma unroll
        for (int ks = 0; ks < 2; ++ks) {
            #pragma unroll
            for (int ni = 0; ni < 4; ++ni) {
                half8 kf = *reinterpret_cast<const half8*>(
                    &Ks[((ks * 4 + l4) * 64 + ni * 16 + l15) * 8]);
                sacc[ni] = __builtin_amdgcn_mfma_f32_16x16x32_f16(qf[ks], kf, sacc[ni], 0, 0, 0);
            }
        }

        float sv[4][4];
        #pragma unroll
        for (int ni = 0; ni < 4; ++ni) {
            #pragma unroll
            for (int r = 0; r < 4; ++r) {
                float x = sacc[ni][r] * SCALE;
                if (CAUSAL && js == iq) {
                    const int sg = js * 64 + ni * 16 + l15;
                    const int qg = iq * 64 + w * 16 + l4 * 4 + r;
                    if (sg > qg) x = -1e30f;
                }
                sv[ni][r] = x;
            }
        }

        #pragma unroll
        for (int r = 0; r < 4; ++r) {
            float rm = fmaxf(fmaxf(sv[0][r], sv[1][r]), fmaxf(sv[2][r], sv[3][r]));
            rm = fmaxf(rm, __shfl_xor(rm, 1));
            rm = fmaxf(rm, __shfl_xor(rm, 2));
            rm = fmaxf(rm, __shfl_xor(rm, 4));
            rm = fmaxf(rm, __shfl_xor(rm, 8));
            const float mnew = fmaxf(m_run[r], rm);
            const float corr = __expf(m_run[r] - mnew);
            float p0 = __expf(sv[0][r] - mnew);
            float p1 = __expf(sv[1][r] - mnew);
            float p2 = __expf(sv[2][r] - mnew);
            float p3 = __expf(sv[3][r] - mnew);
            float sum = p0 + p1 + p2 + p3;
            sum += __shfl_xor(sum, 1);
            sum += __shfl_xor(sum, 2);
            sum += __shfl_xor(sum, 4);
            sum += __shfl_xor(sum, 8);
            l_run[r] = l_run[r] * corr + sum;
            m_run[r] = mnew;
            #pragma unroll
            for (int ni = 0; ni < 4; ++ni) oacc[ni][r] *= corr;
            f16* prow = &Ps[w][(l4 * 4 + r) * 72];
            prow[ 0 + l15] = (f16)p0;
            prow[16 + l15] = (f16)p1;
            prow[32 + l15] = (f16)p2;
            prow[48 + l15] = (f16)p3;
        }

        #pragma unroll
        for (int ks = 0; ks < 2; ++ks) {
            half8 pf = *reinterpret_cast<const half8*>(&Ps[w][l15 * 72 + ks * 32 + l4 * 8]);
            #pragma unroll
            for (int ni = 0; ni < 4; ++ni) {
                half8 vf = *reinterpret_cast<const half8*>(
                    &VT[(ni * 16 + l15) * 72 + ks * 32 + l4 * 8]);
                oacc[ni] = __builtin_amdgcn_mfma_f32_16x16x32_f16(pf, vf, oacc[ni], 0, 0, 0);
            }
        }
    }

    const int b = bh >> 4, h = bh & (HH - 1);
    #pragma unroll
    for (int r = 0; r < 4; ++r) {
        const float inv = 1.0f / l_run[r];
        const int t = iq * 64 + w * 16 + l4 * 4 + r;
        #pragma unroll
        for (int ni = 0; ni < 4; ++ni)
            O[((size_t)(b * TT + t)) * DD + h * HS + ni * 16 + l15] =
                (f16)(oacc[ni][r] * inv);
    }
}

extern "C" void kernel_launch(void* const* d_in, const int* in_sizes, int n_in,
                              void* d_out, int out_size, void* d_ws, size_t ws_size,
                              hipStream_t stream) {
    const float* src      = (const float*)d_in[0];
    const float* att      = (const float*)d_in[1];
    const float* wq_m     = (const float*)d_in[2];
    const float* wk_m     = (const float*)d_in[3];
    const float* wv_m     = (const float*)d_in[4];
    const float* proj_m_w = (const float*)d_in[5];
    const float* proj_m_b = (const float*)d_in[6];
    const float* wq_f     = (const float*)d_in[7];
    const float* wk_f     = (const float*)d_in[8];
    const float* wv_f     = (const float*)d_in[9];
    const float* bq_f     = (const float*)d_in[10];
    const float* bk_f     = (const float*)d_in[11];
    const float* bv_f     = (const float*)d_in[12];
    const float* proj_f_w = (const float*)d_in[13];
    const float* proj_f_b = (const float*)d_in[14];
    const float* w1       = (const float*)d_in[15];
    const float* b1       = (const float*)d_in[16];
    const float* w2       = (const float*)d_in[17];
    const float* b2       = (const float*)d_in[18];
    const float* norm_w   = (const float*)d_in[19];

    const size_t M_ = 1024 * 1024;
    f16* wsb = (f16*)d_ws;
    // ws layout (f16 units):
    f16* wt      = wsb;                  //  0..16M  weights
    f16* headbuf = wsb + 16 * M_;        // 16..28M  q_m,k_m,v_m,q_f,k_f,v_f (2M each)
    f16* h1      = wsb + 16 * M_;        // overlays headbuf in FFN phase ([2048][4096])
    f16* xn_s    = wsb + 28 * M_;        // 28..30M
    f16* xn_a    = wsb + 30 * M_;        // 30..32M
    f16* ao      = wsb + 32 * M_;        // 32..34M
    f16* mo_h    = wsb + 34 * M_;        // 34..36M  m_out (f16)
    f16* partH   = wsb + 36 * M_;        // 36..44M  4 x [2048][1024] f16 partials
    // d_out scratch before final write:
    float* biascat = (float*)d_out;                    // 5120 floats
    float* f_out = (float*)d_out;
    float* outp  = (float*)d_out;
    (void)ws_size; (void)in_sizes; (void)n_in;

    const dim3 blk(256);
    const int BIG = 1 << 30;
    const dim3 gQKV(40, 16);       // N=5120, BM=128 -> 640 blocks
    const dim3 gVF(8, 32);         // N=1024, BM=64  -> 256 blocks
    const dim3 gW1(32, 16);        // N=4096, BM=128 -> 512 blocks
    const dim3 gSPLIT(8, 16, 4);   // N=1024, BM=128, K split 4 -> 512 blocks
    const dim3 gRED(2048);

    // ---- prologue: weights + both rmsnorms ----
    wtrans_all<<<dim3(4097), blk, 0, stream>>>(
        wq_m, wk_m, wv_m, proj_m_w, wq_f, wk_f, wv_f, proj_f_w, w1, w2,
        wt, bq_f, bk_f, biascat);
    rms2_kernel<<<dim3(2 * NROWS), blk, 0, stream>>>(src, att, norm_w, xn_s, xn_a);

    // ---- merged QKV_m + Q_f/K_f GEMM: N=5120, cols>=3072 read xn_a ----
    gemm_mfma<128, 64, 1, true, true, true, false><<<gQKV, blk, 0, stream>>>(
        xn_s, xn_a, wt, biascat, nullptr, headbuf, 5120, 1024, 3072);

    // ---- masked self-attention block ----
    attn_mfma<true><<<dim3(16, 32), blk, 0, stream>>>(
        headbuf, headbuf + 2 * M_, headbuf + 4 * M_, ao);
    gemm_mfma<128, 64, 0, false, false, false, true><<<gSPLIT, blk, 0, stream>>>(
        ao, nullptr, wt + 6 * M_, nullptr, nullptr, partH, 1024, 1024, BIG);
    reduce_fuse<0><<<gRED, blk, 0, stream>>>(
        partH, proj_m_b, src, nullptr, nullptr, mo_h, nullptr, nullptr);

    // ---- cross attention block: v_f from m_out ----
    gemm_mfma<64, 64, 1, true, false, true, false><<<gVF, blk, 0, stream>>>(
        mo_h, nullptr, wt + 5 * M_, bv_f, nullptr, headbuf + 10 * M_, 1024, 1024, BIG);
    attn_mfma<false><<<dim3(16, 32), blk, 0, stream>>>(
        headbuf + 6 * M_, headbuf + 8 * M_, headbuf + 10 * M_, ao);
    gemm_mfma<128, 64, 0, false, false, false, true><<<gSPLIT, blk, 0, stream>>>(
        ao, nullptr, wt + 7 * M_, nullptr, nullptr, partH, 1024, 1024, BIG);
    reduce_fuse<1><<<gRED, blk, 0, stream>>>(
        partH, proj_f_b, nullptr, mo_h, f_out, nullptr, norm_w, xn_s);

    // ---- FFN block ----
    gemm_mfma<128, 64, 2, false, false, true, false><<<gW1, blk, 0, stream>>>(
        xn_s, nullptr, wt + 8 * M_, b1, nullptr, h1, 4096, 1024, BIG);
    gemm_mfma<128, 64, 0, false, false, false, true><<<gSPLIT, blk, 0, stream>>>(
        h1, nullptr, wt + 12 * M_, nullptr, nullptr, partH, 1024, 4096, BIG);
    reduce_fuse<2><<<gRED, blk, 0, stream>>>(
        partH, b2, f_out, nullptr, outp, nullptr, nullptr, nullptr);
}

// Round 11
// 319.333 us; speedup vs baseline: 1.0012x; 1.0012x over previous
//
#include <hip/hip_runtime.h>
#include <math.h>

#define BB 2
#define TT 1024
#define DD 1024
#define HH 16
#define HS 64
#define NROWS (BB*TT)   // 2048

typedef _Float16 f16;
typedef __attribute__((ext_vector_type(8))) _Float16 half8;
typedef __attribute__((ext_vector_type(4))) _Float16 half4;
typedef __attribute__((ext_vector_type(4))) float f32x4;

constexpr float EPS   = 1e-5f;
constexpr float SCALE = 8.0f;   // faithful bug: scores * sqrt(HS)

__device__ __forceinline__ void load_lds16(const f16* g, f16* l) {
    __builtin_amdgcn_global_load_lds(
        (const __attribute__((address_space(1))) unsigned int*)g,
        (__attribute__((address_space(3))) unsigned int*)l, 16, 0, 0);
}

// counted vmcnt wait + scheduler fence (rule #18)
template<int N>
__device__ __forceinline__ void vm_wait() {
    if constexpr (N == 0) asm volatile("s_waitcnt vmcnt(0)" ::: "memory");
    else if constexpr (N == 3) asm volatile("s_waitcnt vmcnt(3)" ::: "memory");
    else if constexpr (N == 4) asm volatile("s_waitcnt vmcnt(4)" ::: "memory");
    __builtin_amdgcn_sched_barrier(0);
}

// XCD-aware bijective swizzle of the linear block id (total % 8 == 0).
__device__ __forceinline__ int xcd_swizzle(int lin, int total) {
    if ((total & 7) == 0) {
        const int chunk = total >> 3;
        lin = (lin & 7) * chunk + (lin >> 3);
    }
    return lin;
}

// ---------------- dual RMSNorm: rows 0..2047 = src -> xn_s, 2048..4095 = att -> xn_a
__global__ __launch_bounds__(256) void rms2_kernel(const float* __restrict__ src,
                                                   const float* __restrict__ att,
                                                   const float* __restrict__ w,
                                                   f16* __restrict__ xn_s,
                                                   f16* __restrict__ xn_a) {
    const int bid = blockIdx.x;
    const int tid = threadIdx.x;
    const int row = bid & (NROWS - 1);
    const float* xr = ((bid < NROWS) ? src : att) + (size_t)row * DD;
    f16* out = ((bid < NROWS) ? xn_s : xn_a) + (size_t)row * DD;

    float4 xv = reinterpret_cast<const float4*>(xr)[tid];
    float ss = xv.x*xv.x + xv.y*xv.y + xv.z*xv.z + xv.w*xv.w;

    __shared__ float red[256];
    red[tid] = ss; __syncthreads();
    for (int s = 128; s > 0; s >>= 1) {
        if (tid < s) red[tid] += red[tid + s];
        __syncthreads();
    }
    const float inv = rsqrtf(red[0] * (1.0f / DD) + EPS);

    float4 wv = reinterpret_cast<const float4*>(w)[tid];
    half4 o;
    o.x = (f16)(xv.x * inv * wv.x);
    o.y = (f16)(xv.y * inv * wv.y);
    o.z = (f16)(xv.z * inv * wv.z);
    o.w = (f16)(xv.w * inv * wv.w);
    *reinterpret_cast<half4*>(&out[tid * 4]) = o;
}

// ---------------- fused weight prep: all 10 transposes + 5120-bias pack ----------
// wt layout (f16, units of M_=1M): [0:3 qkv_m][3 wq_f][4 wk_f][5 wv_f][6 projm]
//                                  [7 projf][8:12 w1][12:16 w2]
__global__ __launch_bounds__(256) void wtrans_all(
    const float* __restrict__ wq_m, const float* __restrict__ wk_m,
    const float* __restrict__ wv_m, const float* __restrict__ proj_m_w,
    const float* __restrict__ wq_f, const float* __restrict__ wk_f,
    const float* __restrict__ wv_f, const float* __restrict__ proj_f_w,
    const float* __restrict__ w1,   const float* __restrict__ w2,
    f16* __restrict__ wt,
    const float* __restrict__ bq, const float* __restrict__ bk,
    float* __restrict__ biascat)
{
    const int bid = blockIdx.x;
    const int tid = threadIdx.x;
    const size_t M_ = 1024 * 1024;

    if (bid >= 4096) {   // bias pack: [0]*3072 | bq | bk  (5120 floats)
        for (int j = tid; j < 5120; j += 256)
            biascat[j] = (j < 3072) ? 0.f : ((j < 4096) ? bq[j - 3072] : bk[j - 4096]);
        return;
    }

    const float* W; f16* Wt; int K, N, lognk, t; bool headw;
    if (bid < 768)       { const int m = bid >> 8;
                           W = (m == 0) ? wq_m : (m == 1) ? wk_m : wv_m;
                           Wt = wt + (size_t)m * M_;
                           K = 1024; N = 1024; lognk = 4; headw = true;  t = bid & 255; }
    else if (bid < 1024) { W = proj_m_w; Wt = wt + 6 * M_;
                           K = 1024; N = 1024; lognk = 4; headw = false; t = bid - 768; }
    else if (bid < 1792) { const int m = (bid - 1024) >> 8;
                           W = (m == 0) ? wq_f : (m == 1) ? wk_f : wv_f;
                           Wt = wt + (size_t)(3 + m) * M_;
                           K = 1024; N = 1024; lognk = 4; headw = true;  t = (bid - 1024) & 255; }
    else if (bid < 2048) { W = proj_f_w; Wt = wt + 7 * M_;
                           K = 1024; N = 1024; lognk = 4; headw = false; t = bid - 1792; }
    else if (bid < 3072) { W = w1; Wt = wt + 8 * M_;
                           K = 1024; N = 4096; lognk = 4; headw = false; t = bid - 2048; }
    else                 { W = w2; Wt = wt + 12 * M_;
                           K = 4096; N = 1024; lognk = 6; headw = false; t = bid - 3072; }

    const int k0 = (t & ((1 << lognk) - 1)) * 64;
    const int n0 = (t >> lognk) * 64;

    __shared__ float tt[64][65];
    #pragma unroll
    for (int r = 0; r < 4; ++r) {
        const int idx = tid + r * 256;
        const int kl  = idx >> 4;
        const int nl4 = (idx & 15) * 4;
        const float* gp;
        if (headw) {
            gp = W + ((size_t)(n0 >> 6) * K + (k0 + kl)) * 64 + nl4;
        } else {
            gp = W + (size_t)(k0 + kl) * N + n0 + nl4;
        }
        float4 v = *reinterpret_cast<const float4*>(gp);
        tt[kl][nl4 + 0] = v.x; tt[kl][nl4 + 1] = v.y;
        tt[kl][nl4 + 2] = v.z; tt[kl][nl4 + 3] = v.w;
    }
    __syncthreads();
    #pragma unroll
    for (int r = 0; r < 4; ++r) {
        const int idx = tid + r * 256;
        const int nl  = idx >> 4;
        const int kl4 = (idx & 15) * 4;
        half4 o;
        o.x = (f16)tt[kl4 + 0][nl];
        o.y = (f16)tt[kl4 + 1][nl];
        o.z = (f16)tt[kl4 + 2][nl];
        o.w = (f16)tt[kl4 + 3][nl];
        *reinterpret_cast<half4*>(&Wt[(size_t)(n0 + nl) * K + k0 + kl4]) = o;
    }
}

// ---------------- fp16 MFMA GEMM, BM x 128 tiles, BK=32 ------------------------
// Static 2-buffer, unrolled-pair K-loop with COUNTED vmcnt (T4): the older
// stage's loads are waited with vmcnt(STG) while the newer stage's STG loads
// stay in flight across raw s_barrier. Only the final tile drains to 0.
// Per tile: vmcnt(N); barrier; ds_read+MFMA; barrier; restage.
// grid (N/128, M/BM, ksplit). PARTIAL: z writes f16 partials to outH + z*M*N.
// HEADOUT: col -> mat = col>>10, out = outH + mat*2M + head-layout index.
template<int BM, int EPI, bool HEADOUT, bool SPLITA, bool OHALF, bool PARTIAL>
__global__ __launch_bounds__(256, 2) void gemm_mfma(
    const f16* __restrict__ A1,
    const f16* __restrict__ A2,
    const f16* __restrict__ Bt,
    const float* __restrict__ bias,
    float* __restrict__ outF,
    f16* __restrict__ outH,
    int N, int K, int splitN)
{
    constexpr int BK = 32;
    constexpr int MI = 4;
    constexpr int NI = (BM == 128) ? 4 : 2;
    constexpr int WN = (BM == 128) ? 64 : 32;
    constexpr int ASLOT = BM * 4;
    constexpr int AINST = ASLOT / 256;
    constexpr int STG   = AINST + 2;          // global_load_lds per thread per stage

    __shared__ f16 ldsA[2][ASLOT * 8];
    __shared__ f16 ldsB[2][512 * 8];

    const int tid  = threadIdx.x;
    const int lane = tid & 63;
    const int wid  = tid >> 6;
    const int gy = gridDim.y;
    const int lin = xcd_swizzle(blockIdx.y * gridDim.x + blockIdx.x,
                                gridDim.x * gy);
    const int m0 = (lin % gy) * BM;
    const int n0 = (lin / gy) * 128;
    const int wm = (BM == 128) ? (wid >> 1) : 0;
    const int wn = (BM == 128) ? (wid & 1) : wid;

    const int Klen  = K / gridDim.z;
    const int kbase = blockIdx.z * Klen;

    const f16* Aptr = (SPLITA && n0 >= splitN) ? A2 : A1;

    f32x4 acc[MI][NI];
    #pragma unroll
    for (int i = 0; i < MI; ++i)
        #pragma unroll
        for (int j = 0; j < NI; ++j)
            acc[i][j] = (f32x4){0.f, 0.f, 0.f, 0.f};

    auto stage = [&](int buf, int kt) {
        const int k0 = kbase + kt * BK;
        #pragma unroll
        for (int i = 0; i < AINST; ++i) {
            const int s   = (wid * AINST + i) * 64 + lane;
            const int kh  = s / BM;
            const int row = s % BM;
            load_lds16(Aptr + (size_t)(m0 + row) * K + (k0 + kh * 8),
                       &ldsA[buf][s * 8]);
        }
        #pragma unroll
        for (int i = 0; i < 2; ++i) {
            const int s   = (wid * 2 + i) * 64 + lane;
            const int kh  = s >> 7;
            const int col = s & 127;
            load_lds16(Bt + (size_t)(n0 + col) * K + (k0 + kh * 8),
                       &ldsB[buf][s * 8]);
        }
    };

    const int l15 = lane & 15, l4 = lane >> 4;
    auto compute = [&](int buf) {
        half8 af[MI], bfr[NI];
        #pragma unroll
        for (int mi = 0; mi < MI; ++mi)
            af[mi] = *reinterpret_cast<const half8*>(
                &ldsA[buf][(l4 * BM + wm * 64 + mi * 16 + l15) * 8]);
        #pragma unroll
        for (int ni = 0; ni < NI; ++ni)
            bfr[ni] = *reinterpret_cast<const half8*>(
                &ldsB[buf][(l4 * 128 + wn * WN + ni * 16 + l15) * 8]);
        #pragma unroll
        for (int mi = 0; mi < MI; ++mi)
            #pragma unroll
            for (int ni = 0; ni < NI; ++ni)
                acc[mi][ni] = __builtin_amdgcn_mfma_f32_16x16x32_f16(
                    af[mi], bfr[ni], acc[mi][ni], 0, 0, 0);
    };

    const int NT = Klen / BK;   // even for all configs used (8, 32)
    stage(0, 0);
    stage(1, 1);
    for (int kt = 0; kt < NT; kt += 2) {
        // ---- tile kt in buf0: b1's STG loads stay in flight ----
        vm_wait<STG>();
        __builtin_amdgcn_s_barrier();
        compute(0);
        __builtin_amdgcn_s_barrier();        // all waves done reading buf0
        if (kt + 2 < NT) stage(0, kt + 2);
        // ---- tile kt+1 in buf1 ----
        if (kt + 2 < NT) vm_wait<STG>(); else vm_wait<0>();
        __builtin_amdgcn_s_barrier();
        compute(1);
        if (kt + 2 < NT) {
            __builtin_amdgcn_s_barrier();    // all waves done reading buf1
            stage(1, kt + 3);                // NT even -> kt+3 < NT
        }
    }

    f16* pout = nullptr;
    if (PARTIAL) {
        const size_t MN = (size_t)gridDim.y * BM * N;
        pout = outH + (size_t)blockIdx.z * MN;
    }

    #pragma unroll
    for (int mi = 0; mi < MI; ++mi) {
        #pragma unroll
        for (int ni = 0; ni < NI; ++ni) {
            #pragma unroll
            for (int r = 0; r < 4; ++r) {
                const int row = m0 + wm * 64 + mi * 16 + l4 * 4 + r;
                const int col = n0 + wn * WN + ni * 16 + l15;
                float v = acc[mi][ni][r];
                if (PARTIAL) {
                    pout[(size_t)row * N + col] = (f16)v;
                    continue;
                }
                if (EPI >= 1) v += bias[col];
                if (EPI == 2) v = 0.5f * v * (1.0f + erff(v * 0.70710678118f));
                size_t oidx;
                if (HEADOUT) {
                    const int mat = col >> 10;
                    const int h = (col >> 6) & 15, e = col & 63;
                    const int b = row >> 10, t = row & (TT - 1);
                    oidx = (size_t)mat * ((size_t)NROWS * DD)
                         + ((size_t)((b * HH + h) * TT + t)) * HS + e;
                } else {
                    oidx = (size_t)row * N + col;
                }
                if (OHALF) outH[oidx] = (f16)v;
                else       outF[oidx] = v;
            }
        }
    }
}

// ---------------- split-K reduce epilogues (f16 partials), N=1024, 1 row/block --
// MODE 0: out_h = sum + bias + residF(src)                  [m_out f16]
// MODE 1: outF = sum + bias + residH(m_out); xn = rms(outF) [f_out + fused rmsnorm]
// MODE 2: outF = sum + bias + residF(f_out)                 [final output]
template<int MODE>
__global__ __launch_bounds__(256) void reduce_fuse(const f16* __restrict__ part,
                                                   const float* __restrict__ bias,
                                                   const float* __restrict__ residF,
                                                   const f16* __restrict__ residH,
                                                   float* __restrict__ outF,
                                                   f16* __restrict__ outH,
                                                   const float* __restrict__ normw,
                                                   f16* __restrict__ xnout) {
    const size_t MN  = (size_t)NROWS * 1024;
    const int tid = threadIdx.x;
    const size_t idx = ((size_t)blockIdx.x * 256 + tid) * 4;
    float o[4];
    {
        half4 p0 = *reinterpret_cast<const half4*>(part + idx);
        half4 p1 = *reinterpret_cast<const half4*>(part + MN + idx);
        half4 p2 = *reinterpret_cast<const half4*>(part + 2 * MN + idx);
        half4 p3 = *reinterpret_cast<const half4*>(part + 3 * MN + idx);
        float4 bi = *reinterpret_cast<const float4*>(bias + (idx & 1023));
        o[0] = (float)p0.x + (float)p1.x + (float)p2.x + (float)p3.x + bi.x;
        o[1] = (float)p0.y + (float)p1.y + (float)p2.y + (float)p3.y + bi.y;
        o[2] = (float)p0.z + (float)p1.z + (float)p2.z + (float)p3.z + bi.z;
        o[3] = (float)p0.w + (float)p1.w + (float)p2.w + (float)p3.w + bi.w;
    }
    if (MODE == 0 || MODE == 2) {
        float4 rs = *reinterpret_cast<const float4*>(residF + idx);
        o[0] += rs.x; o[1] += rs.y; o[2] += rs.z; o[3] += rs.w;
    } else {
        half4 rh = *reinterpret_cast<const half4*>(residH + idx);
        o[0] += (float)rh.x; o[1] += (float)rh.y; o[2] += (float)rh.z; o[3] += (float)rh.w;
    }

    if (MODE == 0) {
        half4 h;
        h.x = (f16)o[0]; h.y = (f16)o[1]; h.z = (f16)o[2]; h.w = (f16)o[3];
        *reinterpret_cast<half4*>(outH + idx) = h;
        return;
    }

    float4 ov = {o[0], o[1], o[2], o[3]};
    *reinterpret_cast<float4*>(outF + idx) = ov;

    if (MODE == 1) {   // fused rmsnorm of the row (block == one row of 1024)
        __shared__ float red[256];
        red[tid] = o[0]*o[0] + o[1]*o[1] + o[2]*o[2] + o[3]*o[3];
        __syncthreads();
        for (int s = 128; s > 0; s >>= 1) {
            if (tid < s) red[tid] += red[tid + s];
            __syncthreads();
        }
        const float inv = rsqrtf(red[0] * (1.0f / DD) + EPS);
        float4 nw = *reinterpret_cast<const float4*>(normw + (idx & 1023));
        half4 h;
        h.x = (f16)(o[0] * inv * nw.x);
        h.y = (f16)(o[1] * inv * nw.y);
        h.z = (f16)(o[2] * inv * nw.z);
        h.w = (f16)(o[3] * inv * nw.w);
        *reinterpret_cast<half4*>(xnout + idx) = h;
    }
}

// ---------------- MFMA flash attention (fp16 in/out, fp32 softmax/acc) ----------------
template<bool CAUSAL>
__global__ __launch_bounds__(256) void attn_mfma(const f16* __restrict__ Q,
                                                 const f16* __restrict__ Kg,
                                                 const f16* __restrict__ Vg,
                                                 f16* __restrict__ O) {
    const int iq  = blockIdx.x;
    const int bh  = blockIdx.y;
    const int tid = threadIdx.x;
    const int lane = tid & 63;
    const int w   = tid >> 6;
    const int l15 = lane & 15, l4 = lane >> 4;

    __shared__ f16 Ks[512 * 8];      // slot-major: slot = eh*64 + s
    __shared__ f16 VT[64 * 72];      // VT[e][s], row stride 72
    __shared__ f16 Ps[4][16 * 72];   // per-wave P[q'][s], row stride 72

    const f16* qb = Q  + ((size_t)bh * TT + (size_t)iq * 64) * HS;
    const f16* kb = Kg + (size_t)bh * TT * HS;
    const f16* vb = Vg + (size_t)bh * TT * HS;

    half8 qf[2];
    #pragma unroll
    for (int ks = 0; ks < 2; ++ks)
        qf[ks] = *reinterpret_cast<const half8*>(
            qb + (size_t)(w * 16 + l15) * HS + ks * 32 + l4 * 8);

    f32x4 oacc[4];
    #pragma unroll
    for (int ni = 0; ni < 4; ++ni) oacc[ni] = (f32x4){0.f, 0.f, 0.f, 0.f};
    float m_run[4], l_run[4];
    #pragma unroll
    for (int r = 0; r < 4; ++r) { m_run[r] = -1e30f; l_run[r] = 0.f; }

    const int sp  = lane & 31;
    const int ehv = lane >> 5;
    const int c0  = w * 16 + ehv * 8;

    const int ntiles = CAUSAL ? (iq + 1) : (TT / 64);
    for (int js = 0; js < ntiles; ++js) {
        __syncthreads();

        #pragma unroll
        for (int i = 0; i < 2; ++i) {
            const int slot = (w * 2 + i) * 64 + lane;
            load_lds16(kb + (size_t)(js * 64 + (slot & 63)) * HS + (slot >> 6) * 8,
                       &Ks[slot * 8]);
        }
        {
            const f16* vrow = vb + (size_t)(js * 64 + 2 * sp) * HS + c0;
            uint4 r0 = *reinterpret_cast<const uint4*>(vrow);
            uint4 r1 = *reinterpret_cast<const uint4*>(vrow + HS);
            const unsigned rc0[4] = {r0.x, r0.y, r0.z, r0.w};
            const unsigned rc1[4] = {r1.x, r1.y, r1.z, r1.w};
            #pragma unroll
            for (int i = 0; i < 8; ++i) {
                const unsigned lo = (i & 1) ? (rc0[i >> 1] >> 16) : (rc0[i >> 1] & 0xffffu);
                const unsigned hi = (i & 1) ? (rc1[i >> 1] >> 16) : (rc1[i >> 1] & 0xffffu);
                *reinterpret_cast<unsigned*>(&VT[(c0 + i) * 72 + 2 * sp]) = lo | (hi << 16);
            }
        }
        __syncthreads();

        f32x4 sacc[4];
        #pragma unroll
        for (int ni = 0; ni < 4; ++ni) sacc[ni] = (f32x4){0.f, 0.f, 0.f, 0.f};
        #pragma unroll
        for (int ks = 0; ks < 2; ++ks) {
            #pragma unroll
            for (int ni = 0; ni < 4; ++ni) {
                half8 kf = *reinterpret_cast<const half8*>(
                    &Ks[((ks * 4 + l4) * 64 + ni * 16 + l15) * 8]);
                sacc[ni] = __builtin_amdgcn_mfma_f32_16x16x32_f16(qf[ks], kf, sacc[ni], 0, 0, 0);
            }
        }

        float sv[4][4];
        #pragma unroll
        for (int ni = 0; ni < 4; ++ni) {
            #pragma unroll
            for (int r = 0; r < 4; ++r) {
                float x = sacc[ni][r] * SCALE;
                if (CAUSAL && js == iq) {
                    const int sg = js * 64 + ni * 16 + l15;
                    const int qg = iq * 64 + w * 16 + l4 * 4 + r;
                    if (sg > qg) x = -1e30f;
                }
                sv[ni][r] = x;
            }
        }

        #pragma unroll
        for (int r = 0; r < 4; ++r) {
            float rm = fmaxf(fmaxf(sv[0][r], sv[1][r]), fmaxf(sv[2][r], sv[3][r]));
            rm = fmaxf(rm, __shfl_xor(rm, 1));
            rm = fmaxf(rm, __shfl_xor(rm, 2));
            rm = fmaxf(rm, __shfl_xor(rm, 4));
            rm = fmaxf(rm, __shfl_xor(rm, 8));
            const float mnew = fmaxf(m_run[r], rm);
            const float corr = __expf(m_run[r] - mnew);
            float p0 = __expf(sv[0][r] - mnew);
            float p1 = __expf(sv[1][r] - mnew);
            float p2 = __expf(sv[2][r] - mnew);
            float p3 = __expf(sv[3][r] - mnew);
            float sum = p0 + p1 + p2 + p3;
            sum += __shfl_xor(sum, 1);
            sum += __shfl_xor(sum, 2);
            sum += __shfl_xor(sum, 4);
            sum += __shfl_xor(sum, 8);
            l_run[r] = l_run[r] * corr + sum;
            m_run[r] = mnew;
            #pragma unroll
            for (int ni = 0; ni < 4; ++ni) oacc[ni][r] *= corr;
            f16* prow = &Ps[w][(l4 * 4 + r) * 72];
            prow[ 0 + l15] = (f16)p0;
            prow[16 + l15] = (f16)p1;
            prow[32 + l15] = (f16)p2;
            prow[48 + l15] = (f16)p3;
        }

        #pragma unroll
        for (int ks = 0; ks < 2; ++ks) {
            half8 pf = *reinterpret_cast<const half8*>(&Ps[w][l15 * 72 + ks * 32 + l4 * 8]);
            #pragma unroll
            for (int ni = 0; ni < 4; ++ni) {
                half8 vf = *reinterpret_cast<const half8*>(
                    &VT[(ni * 16 + l15) * 72 + ks * 32 + l4 * 8]);
                oacc[ni] = __builtin_amdgcn_mfma_f32_16x16x32_f16(pf, vf, oacc[ni], 0, 0, 0);
            }
        }
    }

    const int b = bh >> 4, h = bh & (HH - 1);
    #pragma unroll
    for (int r = 0; r < 4; ++r) {
        const float inv = 1.0f / l_run[r];
        const int t = iq * 64 + w * 16 + l4 * 4 + r;
        #pragma unroll
        for (int ni = 0; ni < 4; ++ni)
            O[((size_t)(b * TT + t)) * DD + h * HS + ni * 16 + l15] =
                (f16)(oacc[ni][r] * inv);
    }
}

extern "C" void kernel_launch(void* const* d_in, const int* in_sizes, int n_in,
                              void* d_out, int out_size, void* d_ws, size_t ws_size,
                              hipStream_t stream) {
    const float* src      = (const float*)d_in[0];
    const float* att      = (const float*)d_in[1];
    const float* wq_m     = (const float*)d_in[2];
    const float* wk_m     = (const float*)d_in[3];
    const float* wv_m     = (const float*)d_in[4];
    const float* proj_m_w = (const float*)d_in[5];
    const float* proj_m_b = (const float*)d_in[6];
    const float* wq_f     = (const float*)d_in[7];
    const float* wk_f     = (const float*)d_in[8];
    const float* wv_f     = (const float*)d_in[9];
    const float* bq_f     = (const float*)d_in[10];
    const float* bk_f     = (const float*)d_in[11];
    const float* bv_f     = (const float*)d_in[12];
    const float* proj_f_w = (const float*)d_in[13];
    const float* proj_f_b = (const float*)d_in[14];
    const float* w1       = (const float*)d_in[15];
    const float* b1       = (const float*)d_in[16];
    const float* w2       = (const float*)d_in[17];
    const float* b2       = (const float*)d_in[18];
    const float* norm_w   = (const float*)d_in[19];

    const size_t M_ = 1024 * 1024;
    f16* wsb = (f16*)d_ws;
    // ws layout (f16 units):
    f16* wt      = wsb;                  //  0..16M  weights
    f16* headbuf = wsb + 16 * M_;        // 16..28M  q_m,k_m,v_m,q_f,k_f,v_f (2M each)
    f16* h1      = wsb + 16 * M_;        // overlays headbuf in FFN phase ([2048][4096])
    f16* xn_s    = wsb + 28 * M_;        // 28..30M
    f16* xn_a    = wsb + 30 * M_;        // 30..32M
    f16* ao      = wsb + 32 * M_;        // 32..34M
    f16* mo_h    = wsb + 34 * M_;        // 34..36M  m_out (f16)
    f16* partH   = wsb + 36 * M_;        // 36..44M  4 x [2048][1024] f16 partials
    // d_out scratch before final write:
    float* biascat = (float*)d_out;                    // 5120 floats
    float* f_out = (float*)d_out;
    float* outp  = (float*)d_out;
    (void)ws_size; (void)in_sizes; (void)n_in;

    const dim3 blk(256);
    const int BIG = 1 << 30;
    const dim3 gQKV(40, 16);       // N=5120, BM=128 -> 640 blocks
    const dim3 gVF(8, 32);         // N=1024, BM=64  -> 256 blocks
    const dim3 gW1(32, 16);        // N=4096, BM=128 -> 512 blocks
    const dim3 gSPLIT(8, 16, 4);   // N=1024, BM=128, K split 4 -> 512 blocks
    const dim3 gRED(2048);

    // ---- prologue: weights + both rmsnorms ----
    wtrans_all<<<dim3(4097), blk, 0, stream>>>(
        wq_m, wk_m, wv_m, proj_m_w, wq_f, wk_f, wv_f, proj_f_w, w1, w2,
        wt, bq_f, bk_f, biascat);
    rms2_kernel<<<dim3(2 * NROWS), blk, 0, stream>>>(src, att, norm_w, xn_s, xn_a);

    // ---- merged QKV_m + Q_f/K_f GEMM: N=5120, cols>=3072 read xn_a ----
    gemm_mfma<128, 1, true, true, true, false><<<gQKV, blk, 0, stream>>>(
        xn_s, xn_a, wt, biascat, nullptr, headbuf, 5120, 1024, 3072);

    // ---- masked self-attention block ----
    attn_mfma<true><<<dim3(16, 32), blk, 0, stream>>>(
        headbuf, headbuf + 2 * M_, headbuf + 4 * M_, ao);
    gemm_mfma<128, 0, false, false, false, true><<<gSPLIT, blk, 0, stream>>>(
        ao, nullptr, wt + 6 * M_, nullptr, nullptr, partH, 1024, 1024, BIG);
    reduce_fuse<0><<<gRED, blk, 0, stream>>>(
        partH, proj_m_b, src, nullptr, nullptr, mo_h, nullptr, nullptr);

    // ---- cross attention block: v_f from m_out ----
    gemm_mfma<64, 1, true, false, true, false><<<gVF, blk, 0, stream>>>(
        mo_h, nullptr, wt + 5 * M_, bv_f, nullptr, headbuf + 10 * M_, 1024, 1024, BIG);
    attn_mfma<false><<<dim3(16, 32), blk, 0, stream>>>(
        headbuf + 6 * M_, headbuf + 8 * M_, headbuf + 10 * M_, ao);
    gemm_mfma<128, 0, false, false, false, true><<<gSPLIT, blk, 0, stream>>>(
        ao, nullptr, wt + 7 * M_, nullptr, nullptr, partH, 1024, 1024, BIG);
    reduce_fuse<1><<<gRED, blk, 0, stream>>>(
        partH, proj_f_b, nullptr, mo_h, f_out, nullptr, norm_w, xn_s);

    // ---- FFN block ----
    gemm_mfma<128, 2, false, false, true, false><<<gW1, blk, 0, stream>>>(
        xn_s, nullptr, wt + 8 * M_, b1, nullptr, h1, 4096, 1024, BIG);
    gemm_mfma<128, 0, false, false, false, true><<<gSPLIT, blk, 0, stream>>>(
        h1, nullptr, wt + 12 * M_, nullptr, nullptr, partH, 1024, 4096, BIG);
    reduce_fuse<2><<<gRED, blk, 0, stream>>>(
        partH, b2, f_out, nullptr, outp, nullptr, nullptr, nullptr);
}

// Round 12
// 310.376 us; speedup vs baseline: 1.0301x; 1.0289x over previous
//
#include <hip/hip_runtime.h>
#include <math.h>

#define BB 2
#define TT 1024
#define DD 1024
#define HH 16
#define HS 64
#define NROWS (BB*TT)   // 2048

typedef _Float16 f16;
typedef __attribute__((ext_vector_type(8))) _Float16 half8;
typedef __attribute__((ext_vector_type(4))) _Float16 half4;
typedef __attribute__((ext_vector_type(4))) float f32x4;

constexpr float EPS   = 1e-5f;
constexpr float SCALE = 8.0f;   // faithful bug: scores * sqrt(HS)

__device__ __forceinline__ void load_lds16(const f16* g, f16* l) {
    __builtin_amdgcn_global_load_lds(
        (const __attribute__((address_space(1))) unsigned int*)g,
        (__attribute__((address_space(3))) unsigned int*)l, 16, 0, 0);
}

// XCD-aware bijective swizzle of the linear block id (total % 8 == 0).
__device__ __forceinline__ int xcd_swizzle(int lin, int total) {
    if ((total & 7) == 0) {
        const int chunk = total >> 3;
        lin = (lin & 7) * chunk + (lin >> 3);
    }
    return lin;
}

// ---------------- fused prologue: 10 weight transposes + bias pack + 2 rmsnorms --
// blocks 0..4095: transpose tiles; 4096: bias pack; 4097..8192: rmsnorm rows
// (0..2047 = src -> xn_s, 2048..4095 = att -> xn_a).
// wt layout (f16, units of M_=1M): [0:3 qkv_m][3 wq_f][4 wk_f][5 wv_f][6 projm]
//                                  [7 projf][8:12 w1][12:16 w2]
__global__ __launch_bounds__(256) void prologue_all(
    const float* __restrict__ wq_m, const float* __restrict__ wk_m,
    const float* __restrict__ wv_m, const float* __restrict__ proj_m_w,
    const float* __restrict__ wq_f, const float* __restrict__ wk_f,
    const float* __restrict__ wv_f, const float* __restrict__ proj_f_w,
    const float* __restrict__ w1,   const float* __restrict__ w2,
    f16* __restrict__ wt,
    const float* __restrict__ bq, const float* __restrict__ bk,
    float* __restrict__ biascat,
    const float* __restrict__ src, const float* __restrict__ att,
    const float* __restrict__ normw,
    f16* __restrict__ xn_s, f16* __restrict__ xn_a)
{
    const int bid = blockIdx.x;
    const int tid = threadIdx.x;
    const size_t M_ = 1024 * 1024;

    __shared__ float tt[64][65];

    if (bid == 4096) {   // bias pack: [0]*3072 | bq | bk  (5120 floats)
        for (int j = tid; j < 5120; j += 256)
            biascat[j] = (j < 3072) ? 0.f : ((j < 4096) ? bq[j - 3072] : bk[j - 4096]);
        return;
    }

    if (bid > 4096) {    // rmsnorm row
        const int rrow = bid - 4097;            // 0..4095
        const int row  = rrow & (NROWS - 1);
        const float* xr = ((rrow < NROWS) ? src : att) + (size_t)row * DD;
        f16* out = ((rrow < NROWS) ? xn_s : xn_a) + (size_t)row * DD;

        float4 xv = reinterpret_cast<const float4*>(xr)[tid];
        float ss = xv.x*xv.x + xv.y*xv.y + xv.z*xv.z + xv.w*xv.w;
        float* red = &tt[0][0];
        red[tid] = ss; __syncthreads();
        for (int s = 128; s > 0; s >>= 1) {
            if (tid < s) red[tid] += red[tid + s];
            __syncthreads();
        }
        const float inv = rsqrtf(red[0] * (1.0f / DD) + EPS);
        float4 wv = reinterpret_cast<const float4*>(normw)[tid];
        half4 o;
        o.x = (f16)(xv.x * inv * wv.x);
        o.y = (f16)(xv.y * inv * wv.y);
        o.z = (f16)(xv.z * inv * wv.z);
        o.w = (f16)(xv.w * inv * wv.w);
        *reinterpret_cast<half4*>(&out[tid * 4]) = o;
        return;
    }

    // weight transpose tile
    const float* W; f16* Wt; int K, N, lognk, t; bool headw;
    if (bid < 768)       { const int m = bid >> 8;
                           W = (m == 0) ? wq_m : (m == 1) ? wk_m : wv_m;
                           Wt = wt + (size_t)m * M_;
                           K = 1024; N = 1024; lognk = 4; headw = true;  t = bid & 255; }
    else if (bid < 1024) { W = proj_m_w; Wt = wt + 6 * M_;
                           K = 1024; N = 1024; lognk = 4; headw = false; t = bid - 768; }
    else if (bid < 1792) { const int m = (bid - 1024) >> 8;
                           W = (m == 0) ? wq_f : (m == 1) ? wk_f : wv_f;
                           Wt = wt + (size_t)(3 + m) * M_;
                           K = 1024; N = 1024; lognk = 4; headw = true;  t = (bid - 1024) & 255; }
    else if (bid < 2048) { W = proj_f_w; Wt = wt + 7 * M_;
                           K = 1024; N = 1024; lognk = 4; headw = false; t = bid - 1792; }
    else if (bid < 3072) { W = w1; Wt = wt + 8 * M_;
                           K = 1024; N = 4096; lognk = 4; headw = false; t = bid - 2048; }
    else                 { W = w2; Wt = wt + 12 * M_;
                           K = 4096; N = 1024; lognk = 6; headw = false; t = bid - 3072; }

    const int k0 = (t & ((1 << lognk) - 1)) * 64;
    const int n0 = (t >> lognk) * 64;

    #pragma unroll
    for (int r = 0; r < 4; ++r) {
        const int idx = tid + r * 256;
        const int kl  = idx >> 4;
        const int nl4 = (idx & 15) * 4;
        const float* gp;
        if (headw) {
            gp = W + ((size_t)(n0 >> 6) * K + (k0 + kl)) * 64 + nl4;
        } else {
            gp = W + (size_t)(k0 + kl) * N + n0 + nl4;
        }
        float4 v = *reinterpret_cast<const float4*>(gp);
        tt[kl][nl4 + 0] = v.x; tt[kl][nl4 + 1] = v.y;
        tt[kl][nl4 + 2] = v.z; tt[kl][nl4 + 3] = v.w;
    }
    __syncthreads();
    #pragma unroll
    for (int r = 0; r < 4; ++r) {
        const int idx = tid + r * 256;
        const int nl  = idx >> 4;
        const int kl4 = (idx & 15) * 4;
        half4 o;
        o.x = (f16)tt[kl4 + 0][nl];
        o.y = (f16)tt[kl4 + 1][nl];
        o.z = (f16)tt[kl4 + 2][nl];
        o.w = (f16)tt[kl4 + 3][nl];
        *reinterpret_cast<half4*>(&Wt[(size_t)(n0 + nl) * K + k0 + kl4]) = o;
    }
}

// ---------------- fp16 MFMA GEMM, BM x 128 tiles, BK=32, 2-buffer --------------
// Round-9 proven structure: stage(next) issued before compute(cur), one
// __syncthreads per K-step. Column-major block walk under the XCD swizzle.
// grid (N/128, M/BM, ksplit). PARTIAL: z writes f16 partials to outH + z*M*N.
// HEADOUT: col -> mat = col>>10, out = outH + mat*2M + head-layout index.
template<int BM, int EPI, bool HEADOUT, bool SPLITA, bool OHALF, bool PARTIAL>
__global__ __launch_bounds__(256, 2) void gemm_mfma(
    const f16* __restrict__ A1,
    const f16* __restrict__ A2,
    const f16* __restrict__ Bt,
    const float* __restrict__ bias,
    float* __restrict__ outF,
    f16* __restrict__ outH,
    int N, int K, int splitN)
{
    constexpr int BK = 32;
    constexpr int MI = 4;
    constexpr int NI = (BM == 128) ? 4 : 2;
    constexpr int WN = (BM == 128) ? 64 : 32;
    constexpr int ASLOT = BM * 4;
    constexpr int AINST = ASLOT / 256;

    __shared__ f16 ldsA[2][ASLOT * 8];
    __shared__ f16 ldsB[2][512 * 8];

    const int tid  = threadIdx.x;
    const int lane = tid & 63;
    const int wid  = tid >> 6;
    const int gy = gridDim.y;
    const int lin = xcd_swizzle(blockIdx.y * gridDim.x + blockIdx.x,
                                gridDim.x * gy);
    const int m0 = (lin % gy) * BM;
    const int n0 = (lin / gy) * 128;
    const int wm = (BM == 128) ? (wid >> 1) : 0;
    const int wn = (BM == 128) ? (wid & 1) : wid;

    const int Klen  = K / gridDim.z;
    const int kbase = blockIdx.z * Klen;

    const f16* Aptr = (SPLITA && n0 >= splitN) ? A2 : A1;

    f32x4 acc[MI][NI];
    #pragma unroll
    for (int i = 0; i < MI; ++i)
        #pragma unroll
        for (int j = 0; j < NI; ++j)
            acc[i][j] = (f32x4){0.f, 0.f, 0.f, 0.f};

    auto stage = [&](int buf, int kt) {
        const int k0 = kbase + kt * BK;
        #pragma unroll
        for (int i = 0; i < AINST; ++i) {
            const int s   = (wid * AINST + i) * 64 + lane;
            const int kh  = s / BM;
            const int row = s % BM;
            load_lds16(Aptr + (size_t)(m0 + row) * K + (k0 + kh * 8),
                       &ldsA[buf][s * 8]);
        }
        #pragma unroll
        for (int i = 0; i < 2; ++i) {
            const int s   = (wid * 2 + i) * 64 + lane;
            const int kh  = s >> 7;
            const int col = s & 127;
            load_lds16(Bt + (size_t)(n0 + col) * K + (k0 + kh * 8),
                       &ldsB[buf][s * 8]);
        }
    };

    const int NT = Klen / BK;
    stage(0, 0);
    __syncthreads();
    int cur = 0;
    const int l15 = lane & 15, l4 = lane >> 4;
    for (int kt = 0; kt < NT; ++kt) {
        if (kt + 1 < NT) stage(cur ^ 1, kt + 1);
        half8 af[MI], bfr[NI];
        #pragma unroll
        for (int mi = 0; mi < MI; ++mi)
            af[mi] = *reinterpret_cast<const half8*>(
                &ldsA[cur][(l4 * BM + wm * 64 + mi * 16 + l15) * 8]);
        #pragma unroll
        for (int ni = 0; ni < NI; ++ni)
            bfr[ni] = *reinterpret_cast<const half8*>(
                &ldsB[cur][(l4 * 128 + wn * WN + ni * 16 + l15) * 8]);
        #pragma unroll
        for (int mi = 0; mi < MI; ++mi)
            #pragma unroll
            for (int ni = 0; ni < NI; ++ni)
                acc[mi][ni] = __builtin_amdgcn_mfma_f32_16x16x32_f16(
                    af[mi], bfr[ni], acc[mi][ni], 0, 0, 0);
        __syncthreads();
        cur ^= 1;
    }

    f16* pout = nullptr;
    if (PARTIAL) {
        const size_t MN = (size_t)gridDim.y * BM * N;
        pout = outH + (size_t)blockIdx.z * MN;
    }

    #pragma unroll
    for (int mi = 0; mi < MI; ++mi) {
        #pragma unroll
        for (int ni = 0; ni < NI; ++ni) {
            #pragma unroll
            for (int r = 0; r < 4; ++r) {
                const int row = m0 + wm * 64 + mi * 16 + l4 * 4 + r;
                const int col = n0 + wn * WN + ni * 16 + l15;
                float v = acc[mi][ni][r];
                if (PARTIAL) {
                    pout[(size_t)row * N + col] = (f16)v;
                    continue;
                }
                if (EPI >= 1) v += bias[col];
                if (EPI == 2) v = 0.5f * v * (1.0f + erff(v * 0.70710678118f));
                size_t oidx;
                if (HEADOUT) {
                    const int mat = col >> 10;
                    const int h = (col >> 6) & 15, e = col & 63;
                    const int b = row >> 10, t = row & (TT - 1);
                    oidx = (size_t)mat * ((size_t)NROWS * DD)
                         + ((size_t)((b * HH + h) * TT + t)) * HS + e;
                } else {
                    oidx = (size_t)row * N + col;
                }
                if (OHALF) outH[oidx] = (f16)v;
                else       outF[oidx] = v;
            }
        }
    }
}

// ---------------- split-K reduce epilogues (f16 partials), N=1024, 1 row/block --
// MODE 0: out_h = sum4 + bias + residF(src)                  [m_out f16]
// MODE 1: outF = sum4 + bias + residH(m_out); xn = rms(outF) [f_out + fused rms]
// MODE 2: outF = sum4 + bias + residF(f_out)                 [final output]
template<int MODE>
__global__ __launch_bounds__(256) void reduce_fuse(const f16* __restrict__ part,
                                                   const float* __restrict__ bias,
                                                   const float* __restrict__ residF,
                                                   const f16* __restrict__ residH,
                                                   float* __restrict__ outF,
                                                   f16* __restrict__ outH,
                                                   const float* __restrict__ normw,
                                                   f16* __restrict__ xnout) {
    const size_t MN  = (size_t)NROWS * 1024;
    const int tid = threadIdx.x;
    const size_t idx = ((size_t)blockIdx.x * 256 + tid) * 4;
    float o[4];
    {
        half4 p0 = *reinterpret_cast<const half4*>(part + idx);
        half4 p1 = *reinterpret_cast<const half4*>(part + MN + idx);
        half4 p2 = *reinterpret_cast<const half4*>(part + 2 * MN + idx);
        half4 p3 = *reinterpret_cast<const half4*>(part + 3 * MN + idx);
        float4 bi = *reinterpret_cast<const float4*>(bias + (idx & 1023));
        o[0] = (float)p0.x + (float)p1.x + (float)p2.x + (float)p3.x + bi.x;
        o[1] = (float)p0.y + (float)p1.y + (float)p2.y + (float)p3.y + bi.y;
        o[2] = (float)p0.z + (float)p1.z + (float)p2.z + (float)p3.z + bi.z;
        o[3] = (float)p0.w + (float)p1.w + (float)p2.w + (float)p3.w + bi.w;
    }
    if (MODE == 0 || MODE == 2) {
        float4 rs = *reinterpret_cast<const float4*>(residF + idx);
        o[0] += rs.x; o[1] += rs.y; o[2] += rs.z; o[3] += rs.w;
    } else {
        half4 rh = *reinterpret_cast<const half4*>(residH + idx);
        o[0] += (float)rh.x; o[1] += (float)rh.y; o[2] += (float)rh.z; o[3] += (float)rh.w;
    }

    if (MODE == 0) {
        half4 h;
        h.x = (f16)o[0]; h.y = (f16)o[1]; h.z = (f16)o[2]; h.w = (f16)o[3];
        *reinterpret_cast<half4*>(outH + idx) = h;
        return;
    }

    float4 ov = {o[0], o[1], o[2], o[3]};
    *reinterpret_cast<float4*>(outF + idx) = ov;

    if (MODE == 1) {   // fused rmsnorm of the row (block == one row of 1024)
        __shared__ float red[256];
        red[tid] = o[0]*o[0] + o[1]*o[1] + o[2]*o[2] + o[3]*o[3];
        __syncthreads();
        for (int s = 128; s > 0; s >>= 1) {
            if (tid < s) red[tid] += red[tid + s];
            __syncthreads();
        }
        const float inv = rsqrtf(red[0] * (1.0f / DD) + EPS);
        float4 nw = *reinterpret_cast<const float4*>(normw + (idx & 1023));
        half4 h;
        h.x = (f16)(o[0] * inv * nw.x);
        h.y = (f16)(o[1] * inv * nw.y);
        h.z = (f16)(o[2] * inv * nw.z);
        h.w = (f16)(o[3] * inv * nw.w);
        *reinterpret_cast<half4*>(xnout + idx) = h;
    }
}

// ---------------- w1 split-K(2) reduce + bias + exact GELU -> h1 f16 -----------
__global__ __launch_bounds__(256) void reduce_gelu(const f16* __restrict__ part,
                                                   const float* __restrict__ b1,
                                                   f16* __restrict__ h1out) {
    const size_t MN  = (size_t)NROWS * 4096;
    const size_t idx = ((size_t)blockIdx.x * 256 + threadIdx.x) * 4;
    half4 p0 = *reinterpret_cast<const half4*>(part + idx);
    half4 p1 = *reinterpret_cast<const half4*>(part + MN + idx);
    float4 bi = *reinterpret_cast<const float4*>(b1 + (idx & 4095));
    float o[4];
    o[0] = (float)p0.x + (float)p1.x + bi.x;
    o[1] = (float)p0.y + (float)p1.y + bi.y;
    o[2] = (float)p0.z + (float)p1.z + bi.z;
    o[3] = (float)p0.w + (float)p1.w + bi.w;
    half4 h;
    #pragma unroll
    for (int j = 0; j < 4; ++j)
        o[j] = 0.5f * o[j] * (1.0f + erff(o[j] * 0.70710678118f));
    h.x = (f16)o[0]; h.y = (f16)o[1]; h.z = (f16)o[2]; h.w = (f16)o[3];
    *reinterpret_cast<half4*>(h1out + idx) = h;
}

// ---------------- MFMA flash attention (fp16 in/out, fp32 softmax/acc) ----------------
template<bool CAUSAL>
__global__ __launch_bounds__(256) void attn_mfma(const f16* __restrict__ Q,
                                                 const f16* __restrict__ Kg,
                                                 const f16* __restrict__ Vg,
                                                 f16* __restrict__ O) {
    const int iq  = blockIdx.x;
    const int bh  = blockIdx.y;
    const int tid = threadIdx.x;
    const int lane = tid & 63;
    const int w   = tid >> 6;
    const int l15 = lane & 15, l4 = lane >> 4;

    __shared__ f16 Ks[512 * 8];      // slot-major: slot = eh*64 + s
    __shared__ f16 VT[64 * 72];      // VT[e][s], row stride 72
    __shared__ f16 Ps[4][16 * 72];   // per-wave P[q'][s], row stride 72

    const f16* qb = Q  + ((size_t)bh * TT + (size_t)iq * 64) * HS;
    const f16* kb = Kg + (size_t)bh * TT * HS;
    const f16* vb = Vg + (size_t)bh * TT * HS;

    half8 qf[2];
    #pragma unroll
    for (int ks = 0; ks < 2; ++ks)
        qf[ks] = *reinterpret_cast<const half8*>(
            qb + (size_t)(w * 16 + l15) * HS + ks * 32 + l4 * 8);

    f32x4 oacc[4];
    #pragma unroll
    for (int ni = 0; ni < 4; ++ni) oacc[ni] = (f32x4){0.f, 0.f, 0.f, 0.f};
    float m_run[4], l_run[4];
    #pragma unroll
    for (int r = 0; r < 4; ++r) { m_run[r] = -1e30f; l_run[r] = 0.f; }

    const int sp  = lane & 31;
    const int ehv = lane >> 5;
    const int c0  = w * 16 + ehv * 8;

    const int ntiles = CAUSAL ? (iq + 1) : (TT / 64);
    for (int js = 0; js < ntiles; ++js) {
        __syncthreads();

        #pragma unroll
        for (int i = 0; i < 2; ++i) {
            const int slot = (w * 2 + i) * 64 + lane;
            load_lds16(kb + (size_t)(js * 64 + (slot & 63)) * HS + (slot >> 6) * 8,
                       &Ks[slot * 8]);
        }
        {
            const f16* vrow = vb + (size_t)(js * 64 + 2 * sp) * HS + c0;
            uint4 r0 = *reinterpret_cast<const uint4*>(vrow);
            uint4 r1 = *reinterpret_cast<const uint4*>(vrow + HS);
            const unsigned rc0[4] = {r0.x, r0.y, r0.z, r0.w};
            const unsigned rc1[4] = {r1.x, r1.y, r1.z, r1.w};
            #pragma unroll
            for (int i = 0; i < 8; ++i) {
                const unsigned lo = (i & 1) ? (rc0[i >> 1] >> 16) : (rc0[i >> 1] & 0xffffu);
                const unsigned hi = (i & 1) ? (rc1[i >> 1] >> 16) : (rc1[i >> 1] & 0xffffu);
                *reinterpret_cast<unsigned*>(&VT[(c0 + i) * 72 + 2 * sp]) = lo | (hi << 16);
            }
        }
        __syncthreads();

        f32x4 sacc[4];
        #pragma unroll
        for (int ni = 0; ni < 4; ++ni) sacc[ni] = (f32x4){0.f, 0.f, 0.f, 0.f};
        __builtin_amdgcn_s_setprio(1);
        #pragma unroll
        for (int ks = 0; ks < 2; ++ks) {
            #pragma unroll
            for (int ni = 0; ni < 4; ++ni) {
                half8 kf = *reinterpret_cast<const half8*>(
                    &Ks[((ks * 4 + l4) * 64 + ni * 16 + l15) * 8]);
                sacc[ni] = __builtin_amdgcn_mfma_f32_16x16x32_f16(qf[ks], kf, sacc[ni], 0, 0, 0);
            }
        }
        __builtin_amdgcn_s_setprio(0);

        float sv[4][4];
        #pragma unroll
        for (int ni = 0; ni < 4; ++ni) {
            #pragma unroll
            for (int r = 0; r < 4; ++r) {
                float x = sacc[ni][r] * SCALE;
                if (CAUSAL && js == iq) {
                    const int sg = js * 64 + ni * 16 + l15;
                    const int qg = iq * 64 + w * 16 + l4 * 4 + r;
                    if (sg > qg) x = -1e30f;
                }
                sv[ni][r] = x;
            }
        }

        #pragma unroll
        for (int r = 0; r < 4; ++r) {
            float rm = fmaxf(fmaxf(sv[0][r], sv[1][r]), fmaxf(sv[2][r], sv[3][r]));
            rm = fmaxf(rm, __shfl_xor(rm, 1));
            rm = fmaxf(rm, __shfl_xor(rm, 2));
            rm = fmaxf(rm, __shfl_xor(rm, 4));
            rm = fmaxf(rm, __shfl_xor(rm, 8));
            const float mnew = fmaxf(m_run[r], rm);
            const float corr = __expf(m_run[r] - mnew);
            float p0 = __expf(sv[0][r] - mnew);
            float p1 = __expf(sv[1][r] - mnew);
            float p2 = __expf(sv[2][r] - mnew);
            float p3 = __expf(sv[3][r] - mnew);
            float sum = p0 + p1 + p2 + p3;
            sum += __shfl_xor(sum, 1);
            sum += __shfl_xor(sum, 2);
            sum += __shfl_xor(sum, 4);
            sum += __shfl_xor(sum, 8);
            l_run[r] = l_run[r] * corr + sum;
            m_run[r] = mnew;
            #pragma unroll
            for (int ni = 0; ni < 4; ++ni) oacc[ni][r] *= corr;
            f16* prow = &Ps[w][(l4 * 4 + r) * 72];
            prow[ 0 + l15] = (f16)p0;
            prow[16 + l15] = (f16)p1;
            prow[32 + l15] = (f16)p2;
            prow[48 + l15] = (f16)p3;
        }

        __builtin_amdgcn_s_setprio(1);
        #pragma unroll
        for (int ks = 0; ks < 2; ++ks) {
            half8 pf = *reinterpret_cast<const half8*>(&Ps[w][l15 * 72 + ks * 32 + l4 * 8]);
            #pragma unroll
            for (int ni = 0; ni < 4; ++ni) {
                half8 vf = *reinterpret_cast<const half8*>(
                    &VT[(ni * 16 + l15) * 72 + ks * 32 + l4 * 8]);
                oacc[ni] = __builtin_amdgcn_mfma_f32_16x16x32_f16(pf, vf, oacc[ni], 0, 0, 0);
            }
        }
        __builtin_amdgcn_s_setprio(0);
    }

    const int b = bh >> 4, h = bh & (HH - 1);
    #pragma unroll
    for (int r = 0; r < 4; ++r) {
        const float inv = 1.0f / l_run[r];
        const int t = iq * 64 + w * 16 + l4 * 4 + r;
        #pragma unroll
        for (int ni = 0; ni < 4; ++ni)
            O[((size_t)(b * TT + t)) * DD + h * HS + ni * 16 + l15] =
                (f16)(oacc[ni][r] * inv);
    }
}

extern "C" void kernel_launch(void* const* d_in, const int* in_sizes, int n_in,
                              void* d_out, int out_size, void* d_ws, size_t ws_size,
                              hipStream_t stream) {
    const float* src      = (const float*)d_in[0];
    const float* att      = (const float*)d_in[1];
    const float* wq_m     = (const float*)d_in[2];
    const float* wk_m     = (const float*)d_in[3];
    const float* wv_m     = (const float*)d_in[4];
    const float* proj_m_w = (const float*)d_in[5];
    const float* proj_m_b = (const float*)d_in[6];
    const float* wq_f     = (const float*)d_in[7];
    const float* wk_f     = (const float*)d_in[8];
    const float* wv_f     = (const float*)d_in[9];
    const float* bq_f     = (const float*)d_in[10];
    const float* bk_f     = (const float*)d_in[11];
    const float* bv_f     = (const float*)d_in[12];
    const float* proj_f_w = (const float*)d_in[13];
    const float* proj_f_b = (const float*)d_in[14];
    const float* w1       = (const float*)d_in[15];
    const float* b1       = (const float*)d_in[16];
    const float* w2       = (const float*)d_in[17];
    const float* b2       = (const float*)d_in[18];
    const float* norm_w   = (const float*)d_in[19];

    const size_t M_ = 1024 * 1024;
    f16* wsb = (f16*)d_ws;
    // ws layout (f16 units), peak 46M f16 = 92MB (proven OK in earlier rounds):
    f16* wt      = wsb;                  //  0..16M  weights
    f16* headbuf = wsb + 16 * M_;        // 16..28M  q_m,k_m,v_m,q_f,k_f,v_f (2M each)
    f16* h1      = wsb + 16 * M_;        // 16..24M  FFN hidden (overlays headbuf)
    f16* xn_s    = wsb + 28 * M_;        // 28..30M  rms(src)
    f16* xn_a    = wsb + 30 * M_;        // 30..32M  rms(att)
    f16* ao      = wsb + 32 * M_;        // 32..34M  attn out
    f16* mo_h    = wsb + 34 * M_;        // 34..36M  m_out (f16)
    f16* partH   = wsb + 36 * M_;        // 36..44M  4 x [2048][1024] f16 partials
    f16* partW1  = wsb + 28 * M_;        // 28..44M  2 x [2048][4096] f16 (FFN phase;
                                         //          xn_s/xn_a/ao/mo_h/partH all dead)
    f16* xn2     = wsb + 44 * M_;        // 44..46M  rms(f_out) = FFN input
    // d_out scratch before final write:
    float* biascat = (float*)d_out;                    // 5120 floats
    float* f_out = (float*)d_out;
    float* outp  = (float*)d_out;
    (void)ws_size; (void)in_sizes; (void)n_in;

    const dim3 blk(256);
    const int BIG = 1 << 30;
    const dim3 gQKV(40, 16);       // N=5120, BM=128 -> 640 blocks
    const dim3 gVF(8, 32);         // N=1024, BM=64  -> 256 blocks
    const dim3 gW1(32, 16, 2);     // N=4096, BM=128, K split 2 -> 1024 blocks
    const dim3 gSPLIT(8, 16, 4);   // N=1024, BM=128, K split 4 -> 512 blocks
    const dim3 gRED(2048);
    const dim3 gREDW1(8192);       // 2048*4096 / (256*4)

    // ---- fused prologue: weights + bias pack + both rmsnorms ----
    prologue_all<<<dim3(8193), blk, 0, stream>>>(
        wq_m, wk_m, wv_m, proj_m_w, wq_f, wk_f, wv_f, proj_f_w, w1, w2,
        wt, bq_f, bk_f, biascat, src, att, norm_w, xn_s, xn_a);

    // ---- merged QKV_m + Q_f/K_f GEMM: N=5120, cols>=3072 read xn_a ----
    gemm_mfma<128, 1, true, true, true, false><<<gQKV, blk, 0, stream>>>(
        xn_s, xn_a, wt, biascat, nullptr, headbuf, 5120, 1024, 3072);

    // ---- masked self-attention block ----
    attn_mfma<true><<<dim3(16, 32), blk, 0, stream>>>(
        headbuf, headbuf + 2 * M_, headbuf + 4 * M_, ao);
    gemm_mfma<128, 0, false, false, false, true><<<gSPLIT, blk, 0, stream>>>(
        ao, nullptr, wt + 6 * M_, nullptr, nullptr, partH, 1024, 1024, BIG);
    reduce_fuse<0><<<gRED, blk, 0, stream>>>(
        partH, proj_m_b, src, nullptr, nullptr, mo_h, nullptr, nullptr);

    // ---- cross attention block: v_f from m_out ----
    gemm_mfma<64, 1, true, false, true, false><<<gVF, blk, 0, stream>>>(
        mo_h, nullptr, wt + 5 * M_, bv_f, nullptr, headbuf + 10 * M_, 1024, 1024, BIG);
    attn_mfma<false><<<dim3(16, 32), blk, 0, stream>>>(
        headbuf + 6 * M_, headbuf + 8 * M_, headbuf + 10 * M_, ao);
    gemm_mfma<128, 0, false, false, false, true><<<gSPLIT, blk, 0, stream>>>(
        ao, nullptr, wt + 7 * M_, nullptr, nullptr, partH, 1024, 1024, BIG);
    reduce_fuse<1><<<gRED, blk, 0, stream>>>(
        partH, proj_f_b, nullptr, mo_h, f_out, nullptr, norm_w, xn2);

    // ---- FFN block: w1 split-K(2) -> gelu-reduce -> w2 split-K(4) ----
    gemm_mfma<128, 0, false, false, false, true><<<gW1, blk, 0, stream>>>(
        xn2, nullptr, wt + 8 * M_, nullptr, nullptr, partW1, 4096, 1024, BIG);
    reduce_gelu<<<gREDW1, blk, 0, stream>>>(partW1, b1, h1);
    gemm_mfma<128, 0, false, false, false, true><<<gSPLIT, blk, 0, stream>>>(
        h1, nullptr, wt + 12 * M_, nullptr, nullptr, partH, 1024, 4096, BIG);
    reduce_fuse<2><<<gRED, blk, 0, stream>>>(
        partH, b2, f_out, nullptr, outp, nullptr, nullptr, nullptr);
}

// Round 13
// 295.672 us; speedup vs baseline: 1.0814x; 1.0497x over previous
//
#include <hip/hip_runtime.h>
#include <math.h>

#define BB 2
#define TT 1024
#define DD 1024
#define HH 16
#define HS 64
#define NROWS (BB*TT)   // 2048

typedef _Float16 f16;
typedef __attribute__((ext_vector_type(8))) _Float16 half8;
typedef __attribute__((ext_vector_type(4))) _Float16 half4;
typedef __attribute__((ext_vector_type(4))) float f32x4;

constexpr float EPS   = 1e-5f;
constexpr float SCALE = 8.0f;   // faithful bug: scores * sqrt(HS)

__device__ __forceinline__ void load_lds16(const f16* g, f16* l) {
    __builtin_amdgcn_global_load_lds(
        (const __attribute__((address_space(1))) unsigned int*)g,
        (__attribute__((address_space(3))) unsigned int*)l, 16, 0, 0);
}

// XCD-aware bijective swizzle of the linear block id (total % 8 == 0).
__device__ __forceinline__ int xcd_swizzle(int lin, int total) {
    if ((total & 7) == 0) {
        const int chunk = total >> 3;
        lin = (lin & 7) * chunk + (lin >> 3);
    }
    return lin;
}

// ---------------- fused prologue: 10 weight transposes + bias pack + 2 rmsnorms --
// blocks 0..4095: transpose tiles; 4096: bias pack; 4097..8192: rmsnorm rows
// (0..2047 = src -> xn_s, 2048..4095 = att -> xn_a).
// wt layout (f16, units of M_=1M): [0:3 qkv_m][3 wq_f][4 wk_f][5 wv_f][6 projm]
//                                  [7 projf][8:12 w1][12:16 w2]
__global__ __launch_bounds__(256) void prologue_all(
    const float* __restrict__ wq_m, const float* __restrict__ wk_m,
    const float* __restrict__ wv_m, const float* __restrict__ proj_m_w,
    const float* __restrict__ wq_f, const float* __restrict__ wk_f,
    const float* __restrict__ wv_f, const float* __restrict__ proj_f_w,
    const float* __restrict__ w1,   const float* __restrict__ w2,
    f16* __restrict__ wt,
    const float* __restrict__ bq, const float* __restrict__ bk,
    float* __restrict__ biascat,
    const float* __restrict__ src, const float* __restrict__ att,
    const float* __restrict__ normw,
    f16* __restrict__ xn_s, f16* __restrict__ xn_a)
{
    const int bid = blockIdx.x;
    const int tid = threadIdx.x;
    const size_t M_ = 1024 * 1024;

    __shared__ float tt[64][65];

    if (bid == 4096) {   // bias pack: [0]*3072 | bq | bk  (5120 floats)
        for (int j = tid; j < 5120; j += 256)
            biascat[j] = (j < 3072) ? 0.f : ((j < 4096) ? bq[j - 3072] : bk[j - 4096]);
        return;
    }

    if (bid > 4096) {    // rmsnorm row
        const int rrow = bid - 4097;            // 0..4095
        const int row  = rrow & (NROWS - 1);
        const float* xr = ((rrow < NROWS) ? src : att) + (size_t)row * DD;
        f16* out = ((rrow < NROWS) ? xn_s : xn_a) + (size_t)row * DD;

        float4 xv = reinterpret_cast<const float4*>(xr)[tid];
        float ss = xv.x*xv.x + xv.y*xv.y + xv.z*xv.z + xv.w*xv.w;
        float* red = &tt[0][0];
        red[tid] = ss; __syncthreads();
        for (int s = 128; s > 0; s >>= 1) {
            if (tid < s) red[tid] += red[tid + s];
            __syncthreads();
        }
        const float inv = rsqrtf(red[0] * (1.0f / DD) + EPS);
        float4 wv = reinterpret_cast<const float4*>(normw)[tid];
        half4 o;
        o.x = (f16)(xv.x * inv * wv.x);
        o.y = (f16)(xv.y * inv * wv.y);
        o.z = (f16)(xv.z * inv * wv.z);
        o.w = (f16)(xv.w * inv * wv.w);
        *reinterpret_cast<half4*>(&out[tid * 4]) = o;
        return;
    }

    // weight transpose tile
    const float* W; f16* Wt; int K, N, lognk, t; bool headw;
    if (bid < 768)       { const int m = bid >> 8;
                           W = (m == 0) ? wq_m : (m == 1) ? wk_m : wv_m;
                           Wt = wt + (size_t)m * M_;
                           K = 1024; N = 1024; lognk = 4; headw = true;  t = bid & 255; }
    else if (bid < 1024) { W = proj_m_w; Wt = wt + 6 * M_;
                           K = 1024; N = 1024; lognk = 4; headw = false; t = bid - 768; }
    else if (bid < 1792) { const int m = (bid - 1024) >> 8;
                           W = (m == 0) ? wq_f : (m == 1) ? wk_f : wv_f;
                           Wt = wt + (size_t)(3 + m) * M_;
                           K = 1024; N = 1024; lognk = 4; headw = true;  t = (bid - 1024) & 255; }
    else if (bid < 2048) { W = proj_f_w; Wt = wt + 7 * M_;
                           K = 1024; N = 1024; lognk = 4; headw = false; t = bid - 1792; }
    else if (bid < 3072) { W = w1; Wt = wt + 8 * M_;
                           K = 1024; N = 4096; lognk = 4; headw = false; t = bid - 2048; }
    else                 { W = w2; Wt = wt + 12 * M_;
                           K = 4096; N = 1024; lognk = 6; headw = false; t = bid - 3072; }

    const int k0 = (t & ((1 << lognk) - 1)) * 64;
    const int n0 = (t >> lognk) * 64;

    #pragma unroll
    for (int r = 0; r < 4; ++r) {
        const int idx = tid + r * 256;
        const int kl  = idx >> 4;
        const int nl4 = (idx & 15) * 4;
        const float* gp;
        if (headw) {
            gp = W + ((size_t)(n0 >> 6) * K + (k0 + kl)) * 64 + nl4;
        } else {
            gp = W + (size_t)(k0 + kl) * N + n0 + nl4;
        }
        float4 v = *reinterpret_cast<const float4*>(gp);
        tt[kl][nl4 + 0] = v.x; tt[kl][nl4 + 1] = v.y;
        tt[kl][nl4 + 2] = v.z; tt[kl][nl4 + 3] = v.w;
    }
    __syncthreads();
    #pragma unroll
    for (int r = 0; r < 4; ++r) {
        const int idx = tid + r * 256;
        const int nl  = idx >> 4;
        const int kl4 = (idx & 15) * 4;
        half4 o;
        o.x = (f16)tt[kl4 + 0][nl];
        o.y = (f16)tt[kl4 + 1][nl];
        o.z = (f16)tt[kl4 + 2][nl];
        o.w = (f16)tt[kl4 + 3][nl];
        *reinterpret_cast<half4*>(&Wt[(size_t)(n0 + nl) * K + k0 + kl4]) = o;
    }
}

// ---------------- fp16 MFMA GEMM, BM x 128 tiles, BK=32, 2-buffer --------------
// Round-9 proven structure: stage(next) issued before compute(cur), one
// __syncthreads per K-step. Column-major block walk under the XCD swizzle.
// grid (N/128, M/BM, ksplit). PARTIAL: z writes f16 partials to outH + z*M*N.
// HEADOUT: col -> mat = col>>10, out = outH + mat*2M + head-layout index.
template<int BM, int EPI, bool HEADOUT, bool SPLITA, bool OHALF, bool PARTIAL>
__global__ __launch_bounds__(256, 2) void gemm_mfma(
    const f16* __restrict__ A1,
    const f16* __restrict__ A2,
    const f16* __restrict__ Bt,
    const float* __restrict__ bias,
    float* __restrict__ outF,
    f16* __restrict__ outH,
    int N, int K, int splitN)
{
    constexpr int BK = 32;
    constexpr int MI = 4;
    constexpr int NI = (BM == 128) ? 4 : 2;
    constexpr int WN = (BM == 128) ? 64 : 32;
    constexpr int ASLOT = BM * 4;
    constexpr int AINST = ASLOT / 256;

    __shared__ f16 ldsA[2][ASLOT * 8];
    __shared__ f16 ldsB[2][512 * 8];

    const int tid  = threadIdx.x;
    const int lane = tid & 63;
    const int wid  = tid >> 6;
    const int gy = gridDim.y;
    const int lin = xcd_swizzle(blockIdx.y * gridDim.x + blockIdx.x,
                                gridDim.x * gy);
    const int m0 = (lin % gy) * BM;
    const int n0 = (lin / gy) * 128;
    const int wm = (BM == 128) ? (wid >> 1) : 0;
    const int wn = (BM == 128) ? (wid & 1) : wid;

    const int Klen  = K / gridDim.z;
    const int kbase = blockIdx.z * Klen;

    const f16* Aptr = (SPLITA && n0 >= splitN) ? A2 : A1;

    f32x4 acc[MI][NI];
    #pragma unroll
    for (int i = 0; i < MI; ++i)
        #pragma unroll
        for (int j = 0; j < NI; ++j)
            acc[i][j] = (f32x4){0.f, 0.f, 0.f, 0.f};

    auto stage = [&](int buf, int kt) {
        const int k0 = kbase + kt * BK;
        #pragma unroll
        for (int i = 0; i < AINST; ++i) {
            const int s   = (wid * AINST + i) * 64 + lane;
            const int kh  = s / BM;
            const int row = s % BM;
            load_lds16(Aptr + (size_t)(m0 + row) * K + (k0 + kh * 8),
                       &ldsA[buf][s * 8]);
        }
        #pragma unroll
        for (int i = 0; i < 2; ++i) {
            const int s   = (wid * 2 + i) * 64 + lane;
            const int kh  = s >> 7;
            const int col = s & 127;
            load_lds16(Bt + (size_t)(n0 + col) * K + (k0 + kh * 8),
                       &ldsB[buf][s * 8]);
        }
    };

    const int NT = Klen / BK;
    stage(0, 0);
    __syncthreads();
    int cur = 0;
    const int l15 = lane & 15, l4 = lane >> 4;
    for (int kt = 0; kt < NT; ++kt) {
        if (kt + 1 < NT) stage(cur ^ 1, kt + 1);
        half8 af[MI], bfr[NI];
        #pragma unroll
        for (int mi = 0; mi < MI; ++mi)
            af[mi] = *reinterpret_cast<const half8*>(
                &ldsA[cur][(l4 * BM + wm * 64 + mi * 16 + l15) * 8]);
        #pragma unroll
        for (int ni = 0; ni < NI; ++ni)
            bfr[ni] = *reinterpret_cast<const half8*>(
                &ldsB[cur][(l4 * 128 + wn * WN + ni * 16 + l15) * 8]);
        #pragma unroll
        for (int mi = 0; mi < MI; ++mi)
            #pragma unroll
            for (int ni = 0; ni < NI; ++ni)
                acc[mi][ni] = __builtin_amdgcn_mfma_f32_16x16x32_f16(
                    af[mi], bfr[ni], acc[mi][ni], 0, 0, 0);
        __syncthreads();
        cur ^= 1;
    }

    f16* pout = nullptr;
    if (PARTIAL) {
        const size_t MN = (size_t)gridDim.y * BM * N;
        pout = outH + (size_t)blockIdx.z * MN;
    }

    #pragma unroll
    for (int mi = 0; mi < MI; ++mi) {
        #pragma unroll
        for (int ni = 0; ni < NI; ++ni) {
            #pragma unroll
            for (int r = 0; r < 4; ++r) {
                const int row = m0 + wm * 64 + mi * 16 + l4 * 4 + r;
                const int col = n0 + wn * WN + ni * 16 + l15;
                float v = acc[mi][ni][r];
                if (PARTIAL) {
                    pout[(size_t)row * N + col] = (f16)v;
                    continue;
                }
                if (EPI >= 1) v += bias[col];
                if (EPI == 2) v = 0.5f * v * (1.0f + erff(v * 0.70710678118f));
                size_t oidx;
                if (HEADOUT) {
                    const int mat = col >> 10;
                    const int h = (col >> 6) & 15, e = col & 63;
                    const int b = row >> 10, t = row & (TT - 1);
                    oidx = (size_t)mat * ((size_t)NROWS * DD)
                         + ((size_t)((b * HH + h) * TT + t)) * HS + e;
                } else {
                    oidx = (size_t)row * N + col;
                }
                if (OHALF) outH[oidx] = (f16)v;
                else       outF[oidx] = v;
            }
        }
    }
}

// ---------------- split-K reduce epilogues (f16 partials), N=1024, 1 row/block --
// MODE 0: out_h = sum4 + bias + residF(src)                  [m_out f16]
// MODE 1: outF = sum4 + bias + residH(m_out); xn = rms(outF) [f_out + fused rms]
// MODE 2: outF = sum4 + bias + residF(f_out)                 [final output]
template<int MODE>
__global__ __launch_bounds__(256) void reduce_fuse(const f16* __restrict__ part,
                                                   const float* __restrict__ bias,
                                                   const float* __restrict__ residF,
                                                   const f16* __restrict__ residH,
                                                   float* __restrict__ outF,
                                                   f16* __restrict__ outH,
                                                   const float* __restrict__ normw,
                                                   f16* __restrict__ xnout) {
    const size_t MN  = (size_t)NROWS * 1024;
    const int tid = threadIdx.x;
    const size_t idx = ((size_t)blockIdx.x * 256 + tid) * 4;
    float o[4];
    {
        half4 p0 = *reinterpret_cast<const half4*>(part + idx);
        half4 p1 = *reinterpret_cast<const half4*>(part + MN + idx);
        half4 p2 = *reinterpret_cast<const half4*>(part + 2 * MN + idx);
        half4 p3 = *reinterpret_cast<const half4*>(part + 3 * MN + idx);
        float4 bi = *reinterpret_cast<const float4*>(bias + (idx & 1023));
        o[0] = (float)p0.x + (float)p1.x + (float)p2.x + (float)p3.x + bi.x;
        o[1] = (float)p0.y + (float)p1.y + (float)p2.y + (float)p3.y + bi.y;
        o[2] = (float)p0.z + (float)p1.z + (float)p2.z + (float)p3.z + bi.z;
        o[3] = (float)p0.w + (float)p1.w + (float)p2.w + (float)p3.w + bi.w;
    }
    if (MODE == 0 || MODE == 2) {
        float4 rs = *reinterpret_cast<const float4*>(residF + idx);
        o[0] += rs.x; o[1] += rs.y; o[2] += rs.z; o[3] += rs.w;
    } else {
        half4 rh = *reinterpret_cast<const half4*>(residH + idx);
        o[0] += (float)rh.x; o[1] += (float)rh.y; o[2] += (float)rh.z; o[3] += (float)rh.w;
    }

    if (MODE == 0) {
        half4 h;
        h.x = (f16)o[0]; h.y = (f16)o[1]; h.z = (f16)o[2]; h.w = (f16)o[3];
        *reinterpret_cast<half4*>(outH + idx) = h;
        return;
    }

    float4 ov = {o[0], o[1], o[2], o[3]};
    *reinterpret_cast<float4*>(outF + idx) = ov;

    if (MODE == 1) {   // fused rmsnorm of the row (block == one row of 1024)
        __shared__ float red[256];
        red[tid] = o[0]*o[0] + o[1]*o[1] + o[2]*o[2] + o[3]*o[3];
        __syncthreads();
        for (int s = 128; s > 0; s >>= 1) {
            if (tid < s) red[tid] += red[tid + s];
            __syncthreads();
        }
        const float inv = rsqrtf(red[0] * (1.0f / DD) + EPS);
        float4 nw = *reinterpret_cast<const float4*>(normw + (idx & 1023));
        half4 h;
        h.x = (f16)(o[0] * inv * nw.x);
        h.y = (f16)(o[1] * inv * nw.y);
        h.z = (f16)(o[2] * inv * nw.z);
        h.w = (f16)(o[3] * inv * nw.w);
        *reinterpret_cast<half4*>(xnout + idx) = h;
    }
}

// ---------------- v_f split-K(2) reduce + bias + head-layout scatter ------------
// one block per global row t; thread handles 4 cols. out[b,h,t,e] layout.
__global__ __launch_bounds__(256) void reduce_vf(const f16* __restrict__ part,
                                                 const float* __restrict__ bv,
                                                 f16* __restrict__ out) {
    const size_t MN = (size_t)NROWS * 1024;
    const int t   = blockIdx.x;            // 0..2047
    const int tid = threadIdx.x;
    const int n   = tid * 4;               // col 0..1023
    const size_t idx = (size_t)t * 1024 + n;
    half4 p0 = *reinterpret_cast<const half4*>(part + idx);
    half4 p1 = *reinterpret_cast<const half4*>(part + MN + idx);
    float4 bi = *reinterpret_cast<const float4*>(bv + n);
    half4 o;
    o.x = (f16)((float)p0.x + (float)p1.x + bi.x);
    o.y = (f16)((float)p0.y + (float)p1.y + bi.y);
    o.z = (f16)((float)p0.z + (float)p1.z + bi.z);
    o.w = (f16)((float)p0.w + (float)p1.w + bi.w);
    const int b = t >> 10, tl = t & (TT - 1);
    const int h = n >> 6, e = n & (HS - 1);
    *reinterpret_cast<half4*>(
        &out[((size_t)(b * HH + h) * TT + tl) * HS + e]) = o;
}

// ---------------- MFMA flash attention (fp16 in/out, fp32 softmax/acc) ----------------
// CAUSAL: complementary iq remap so block pairs (i, i+256) sharing a CU get
// iq and 15-iq (balances the triangular tile count; mapping is bijective).
template<bool CAUSAL>
__global__ __launch_bounds__(256) void attn_mfma(const f16* __restrict__ Q,
                                                 const f16* __restrict__ Kg,
                                                 const f16* __restrict__ Vg,
                                                 f16* __restrict__ O) {
    int iq, bh;
    if (CAUSAL) {
        bh = blockIdx.y;
        iq = (blockIdx.y < 16) ? blockIdx.x : (15 - blockIdx.x);
    } else {
        iq = blockIdx.x; bh = blockIdx.y;
    }
    const int tid = threadIdx.x;
    const int lane = tid & 63;
    const int w   = tid >> 6;
    const int l15 = lane & 15, l4 = lane >> 4;

    __shared__ f16 Ks[512 * 8];      // slot-major: slot = eh*64 + s
    __shared__ f16 VT[64 * 72];      // VT[e][s], row stride 72
    __shared__ f16 Ps[4][16 * 72];   // per-wave P[q'][s], row stride 72

    const f16* qb = Q  + ((size_t)bh * TT + (size_t)iq * 64) * HS;
    const f16* kb = Kg + (size_t)bh * TT * HS;
    const f16* vb = Vg + (size_t)bh * TT * HS;

    half8 qf[2];
    #pragma unroll
    for (int ks = 0; ks < 2; ++ks)
        qf[ks] = *reinterpret_cast<const half8*>(
            qb + (size_t)(w * 16 + l15) * HS + ks * 32 + l4 * 8);

    f32x4 oacc[4];
    #pragma unroll
    for (int ni = 0; ni < 4; ++ni) oacc[ni] = (f32x4){0.f, 0.f, 0.f, 0.f};
    float m_run[4], l_run[4];
    #pragma unroll
    for (int r = 0; r < 4; ++r) { m_run[r] = -1e30f; l_run[r] = 0.f; }

    const int sp  = lane & 31;
    const int ehv = lane >> 5;
    const int c0  = w * 16 + ehv * 8;

    const int ntiles = CAUSAL ? (iq + 1) : (TT / 64);
    for (int js = 0; js < ntiles; ++js) {
        __syncthreads();

        #pragma unroll
        for (int i = 0; i < 2; ++i) {
            const int slot = (w * 2 + i) * 64 + lane;
            load_lds16(kb + (size_t)(js * 64 + (slot & 63)) * HS + (slot >> 6) * 8,
                       &Ks[slot * 8]);
        }
        {
            const f16* vrow = vb + (size_t)(js * 64 + 2 * sp) * HS + c0;
            uint4 r0 = *reinterpret_cast<const uint4*>(vrow);
            uint4 r1 = *reinterpret_cast<const uint4*>(vrow + HS);
            const unsigned rc0[4] = {r0.x, r0.y, r0.z, r0.w};
            const unsigned rc1[4] = {r1.x, r1.y, r1.z, r1.w};
            #pragma unroll
            for (int i = 0; i < 8; ++i) {
                const unsigned lo = (i & 1) ? (rc0[i >> 1] >> 16) : (rc0[i >> 1] & 0xffffu);
                const unsigned hi = (i & 1) ? (rc1[i >> 1] >> 16) : (rc1[i >> 1] & 0xffffu);
                *reinterpret_cast<unsigned*>(&VT[(c0 + i) * 72 + 2 * sp]) = lo | (hi << 16);
            }
        }
        __syncthreads();

        f32x4 sacc[4];
        #pragma unroll
        for (int ni = 0; ni < 4; ++ni) sacc[ni] = (f32x4){0.f, 0.f, 0.f, 0.f};
        __builtin_amdgcn_s_setprio(1);
        #pragma unroll
        for (int ks = 0; ks < 2; ++ks) {
            #pragma unroll
            for (int ni = 0; ni < 4; ++ni) {
                half8 kf = *reinterpret_cast<const half8*>(
                    &Ks[((ks * 4 + l4) * 64 + ni * 16 + l15) * 8]);
                sacc[ni] = __builtin_amdgcn_mfma_f32_16x16x32_f16(qf[ks], kf, sacc[ni], 0, 0, 0);
            }
        }
        __builtin_amdgcn_s_setprio(0);

        float sv[4][4];
        #pragma unroll
        for (int ni = 0; ni < 4; ++ni) {
            #pragma unroll
            for (int r = 0; r < 4; ++r) {
                float x = sacc[ni][r] * SCALE;
                if (CAUSAL && js == iq) {
                    const int sg = js * 64 + ni * 16 + l15;
                    const int qg = iq * 64 + w * 16 + l4 * 4 + r;
                    if (sg > qg) x = -1e30f;
                }
                sv[ni][r] = x;
            }
        }

        #pragma unroll
        for (int r = 0; r < 4; ++r) {
            float rm = fmaxf(fmaxf(sv[0][r], sv[1][r]), fmaxf(sv[2][r], sv[3][r]));
            rm = fmaxf(rm, __shfl_xor(rm, 1));
            rm = fmaxf(rm, __shfl_xor(rm, 2));
            rm = fmaxf(rm, __shfl_xor(rm, 4));
            rm = fmaxf(rm, __shfl_xor(rm, 8));
            const float mnew = fmaxf(m_run[r], rm);
            const float corr = __expf(m_run[r] - mnew);
            float p0 = __expf(sv[0][r] - mnew);
            float p1 = __expf(sv[1][r] - mnew);
            float p2 = __expf(sv[2][r] - mnew);
            float p3 = __expf(sv[3][r] - mnew);
            float sum = p0 + p1 + p2 + p3;
            sum += __shfl_xor(sum, 1);
            sum += __shfl_xor(sum, 2);
            sum += __shfl_xor(sum, 4);
            sum += __shfl_xor(sum, 8);
            l_run[r] = l_run[r] * corr + sum;
            m_run[r] = mnew;
            #pragma unroll
            for (int ni = 0; ni < 4; ++ni) oacc[ni][r] *= corr;
            f16* prow = &Ps[w][(l4 * 4 + r) * 72];
            prow[ 0 + l15] = (f16)p0;
            prow[16 + l15] = (f16)p1;
            prow[32 + l15] = (f16)p2;
            prow[48 + l15] = (f16)p3;
        }

        __builtin_amdgcn_s_setprio(1);
        #pragma unroll
        for (int ks = 0; ks < 2; ++ks) {
            half8 pf = *reinterpret_cast<const half8*>(&Ps[w][l15 * 72 + ks * 32 + l4 * 8]);
            #pragma unroll
            for (int ni = 0; ni < 4; ++ni) {
                half8 vf = *reinterpret_cast<const half8*>(
                    &VT[(ni * 16 + l15) * 72 + ks * 32 + l4 * 8]);
                oacc[ni] = __builtin_amdgcn_mfma_f32_16x16x32_f16(pf, vf, oacc[ni], 0, 0, 0);
            }
        }
        __builtin_amdgcn_s_setprio(0);
    }

    const int b = bh >> 4, h = bh & (HH - 1);
    #pragma unroll
    for (int r = 0; r < 4; ++r) {
        const float inv = 1.0f / l_run[r];
        const int t = iq * 64 + w * 16 + l4 * 4 + r;
        #pragma unroll
        for (int ni = 0; ni < 4; ++ni)
            O[((size_t)(b * TT + t)) * DD + h * HS + ni * 16 + l15] =
                (f16)(oacc[ni][r] * inv);
    }
}

extern "C" void kernel_launch(void* const* d_in, const int* in_sizes, int n_in,
                              void* d_out, int out_size, void* d_ws, size_t ws_size,
                              hipStream_t stream) {
    const float* src      = (const float*)d_in[0];
    const float* att      = (const float*)d_in[1];
    const float* wq_m     = (const float*)d_in[2];
    const float* wk_m     = (const float*)d_in[3];
    const float* wv_m     = (const float*)d_in[4];
    const float* proj_m_w = (const float*)d_in[5];
    const float* proj_m_b = (const float*)d_in[6];
    const float* wq_f     = (const float*)d_in[7];
    const float* wk_f     = (const float*)d_in[8];
    const float* wv_f     = (const float*)d_in[9];
    const float* bq_f     = (const float*)d_in[10];
    const float* bk_f     = (const float*)d_in[11];
    const float* bv_f     = (const float*)d_in[12];
    const float* proj_f_w = (const float*)d_in[13];
    const float* proj_f_b = (const float*)d_in[14];
    const float* w1       = (const float*)d_in[15];
    const float* b1       = (const float*)d_in[16];
    const float* w2       = (const float*)d_in[17];
    const float* b2       = (const float*)d_in[18];
    const float* norm_w   = (const float*)d_in[19];

    const size_t M_ = 1024 * 1024;
    f16* wsb = (f16*)d_ws;
    // ws layout (f16 units), peak 46M f16 = 92MB (proven OK):
    f16* wt      = wsb;                  //  0..16M  weights
    f16* headbuf = wsb + 16 * M_;        // 16..28M  q_m,k_m,v_m,q_f,k_f,v_f (2M each)
    f16* h1      = wsb + 16 * M_;        // 16..24M  FFN hidden (overlays headbuf)
    f16* xn_s    = wsb + 28 * M_;        // 28..30M  rms(src)
    f16* xn_a    = wsb + 30 * M_;        // 30..32M  rms(att)
    f16* ao      = wsb + 32 * M_;        // 32..34M  attn out
    f16* mo_h    = wsb + 34 * M_;        // 34..36M  m_out (f16)
    f16* partH   = wsb + 36 * M_;        // 36..44M  up to 4 x [2048][1024] f16
    f16* xn2     = wsb + 44 * M_;        // 44..46M  rms(f_out) = FFN input
    // d_out scratch before final write:
    float* biascat = (float*)d_out;                    // 5120 floats
    float* f_out = (float*)d_out;
    float* outp  = (float*)d_out;
    (void)ws_size; (void)in_sizes; (void)n_in;

    const dim3 blk(256);
    const int BIG = 1 << 30;
    const dim3 gQKV(40, 16);       // N=5120, BM=128 -> 640 blocks
    const dim3 gVF(8, 32, 2);      // N=1024, BM=64, K split 2 -> 512 blocks
    const dim3 gW1(32, 16);        // N=4096, BM=128 -> 512 blocks (direct GELU)
    const dim3 gSPLIT(8, 16, 4);   // N=1024, BM=128, K split 4 -> 512 blocks
    const dim3 gRED(2048);

    // ---- fused prologue: weights + bias pack + both rmsnorms ----
    prologue_all<<<dim3(8193), blk, 0, stream>>>(
        wq_m, wk_m, wv_m, proj_m_w, wq_f, wk_f, wv_f, proj_f_w, w1, w2,
        wt, bq_f, bk_f, biascat, src, att, norm_w, xn_s, xn_a);

    // ---- merged QKV_m + Q_f/K_f GEMM: N=5120, cols>=3072 read xn_a ----
    gemm_mfma<128, 1, true, true, true, false><<<gQKV, blk, 0, stream>>>(
        xn_s, xn_a, wt, biascat, nullptr, headbuf, 5120, 1024, 3072);

    // ---- masked self-attention block ----
    attn_mfma<true><<<dim3(16, 32), blk, 0, stream>>>(
        headbuf, headbuf + 2 * M_, headbuf + 4 * M_, ao);
    gemm_mfma<128, 0, false, false, false, true><<<gSPLIT, blk, 0, stream>>>(
        ao, nullptr, wt + 6 * M_, nullptr, nullptr, partH, 1024, 1024, BIG);
    reduce_fuse<0><<<gRED, blk, 0, stream>>>(
        partH, proj_m_b, src, nullptr, nullptr, mo_h, nullptr, nullptr);

    // ---- cross attention block: v_f from m_out (split-K2 + head-scatter reduce) --
    gemm_mfma<64, 0, false, false, false, true><<<gVF, blk, 0, stream>>>(
        mo_h, nullptr, wt + 5 * M_, nullptr, nullptr, partH, 1024, 1024, BIG);
    reduce_vf<<<dim3(NROWS), blk, 0, stream>>>(partH, bv_f, headbuf + 10 * M_);
    attn_mfma<false><<<dim3(16, 32), blk, 0, stream>>>(
        headbuf + 6 * M_, headbuf + 8 * M_, headbuf + 10 * M_, ao);
    gemm_mfma<128, 0, false, false, false, true><<<gSPLIT, blk, 0, stream>>>(
        ao, nullptr, wt + 7 * M_, nullptr, nullptr, partH, 1024, 1024, BIG);
    reduce_fuse<1><<<gRED, blk, 0, stream>>>(
        partH, proj_f_b, nullptr, mo_h, f_out, nullptr, norm_w, xn2);

    // ---- FFN block: w1 direct (bias+GELU fused) -> w2 split-K(4) ----
    gemm_mfma<128, 2, false, false, true, false><<<gW1, blk, 0, stream>>>(
        xn2, nullptr, wt + 8 * M_, b1, nullptr, h1, 4096, 1024, BIG);
    gemm_mfma<128, 0, false, false, false, true><<<gSPLIT, blk, 0, stream>>>(
        h1, nullptr, wt + 12 * M_, nullptr, nullptr, partH, 1024, 4096, BIG);
    reduce_fuse<2><<<gRED, blk, 0, stream>>>(
        partH, b2, f_out, nullptr, outp, nullptr, nullptr, nullptr);
}

// Round 14
// 294.656 us; speedup vs baseline: 1.0851x; 1.0034x over previous
//
#include <hip/hip_runtime.h>
#include <math.h>

#define BB 2
#define TT 1024
#define DD 1024
#define HH 16
#define HS 64
#define NROWS (BB*TT)   // 2048

typedef _Float16 f16;
typedef __attribute__((ext_vector_type(8))) _Float16 half8;
typedef __attribute__((ext_vector_type(4))) _Float16 half4;
typedef __attribute__((ext_vector_type(4))) float f32x4;

constexpr float EPS   = 1e-5f;
constexpr float SCALE = 8.0f;   // faithful bug: scores * sqrt(HS)

__device__ __forceinline__ void load_lds16(const f16* g, f16* l) {
    __builtin_amdgcn_global_load_lds(
        (const __attribute__((address_space(1))) unsigned int*)g,
        (__attribute__((address_space(3))) unsigned int*)l, 16, 0, 0);
}

// XCD-aware bijective swizzle of the linear block id (total % 8 == 0).
__device__ __forceinline__ int xcd_swizzle(int lin, int total) {
    if ((total & 7) == 0) {
        const int chunk = total >> 3;
        lin = (lin & 7) * chunk + (lin >> 3);
    }
    return lin;
}

// ---------------- fused prologue: 10 weight transposes + bias pack + 2 rmsnorms --
// blocks 0..4095: transpose tiles; 4096: bias pack; 4097..8192: rmsnorm rows
// (0..2047 = src -> xn_s, 2048..4095 = att -> xn_a).
// wt layout (f16, units of M_=1M): [0:3 qkv_m][3 wq_f][4 wk_f][5 wv_f][6 projm]
//                                  [7 projf][8:12 w1][12:16 w2]
__global__ __launch_bounds__(256) void prologue_all(
    const float* __restrict__ wq_m, const float* __restrict__ wk_m,
    const float* __restrict__ wv_m, const float* __restrict__ proj_m_w,
    const float* __restrict__ wq_f, const float* __restrict__ wk_f,
    const float* __restrict__ wv_f, const float* __restrict__ proj_f_w,
    const float* __restrict__ w1,   const float* __restrict__ w2,
    f16* __restrict__ wt,
    const float* __restrict__ bq, const float* __restrict__ bk,
    float* __restrict__ biascat,
    const float* __restrict__ src, const float* __restrict__ att,
    const float* __restrict__ normw,
    f16* __restrict__ xn_s, f16* __restrict__ xn_a)
{
    const int bid = blockIdx.x;
    const int tid = threadIdx.x;
    const size_t M_ = 1024 * 1024;

    __shared__ float tt[64][65];

    if (bid == 4096) {   // bias pack: [0]*3072 | bq | bk  (5120 floats)
        for (int j = tid; j < 5120; j += 256)
            biascat[j] = (j < 3072) ? 0.f : ((j < 4096) ? bq[j - 3072] : bk[j - 4096]);
        return;
    }

    if (bid > 4096) {    // rmsnorm row
        const int rrow = bid - 4097;            // 0..4095
        const int row  = rrow & (NROWS - 1);
        const float* xr = ((rrow < NROWS) ? src : att) + (size_t)row * DD;
        f16* out = ((rrow < NROWS) ? xn_s : xn_a) + (size_t)row * DD;

        float4 xv = reinterpret_cast<const float4*>(xr)[tid];
        float ss = xv.x*xv.x + xv.y*xv.y + xv.z*xv.z + xv.w*xv.w;
        float* red = &tt[0][0];
        red[tid] = ss; __syncthreads();
        for (int s = 128; s > 0; s >>= 1) {
            if (tid < s) red[tid] += red[tid + s];
            __syncthreads();
        }
        const float inv = rsqrtf(red[0] * (1.0f / DD) + EPS);
        float4 wv = reinterpret_cast<const float4*>(normw)[tid];
        half4 o;
        o.x = (f16)(xv.x * inv * wv.x);
        o.y = (f16)(xv.y * inv * wv.y);
        o.z = (f16)(xv.z * inv * wv.z);
        o.w = (f16)(xv.w * inv * wv.w);
        *reinterpret_cast<half4*>(&out[tid * 4]) = o;
        return;
    }

    // weight transpose tile
    const float* W; f16* Wt; int K, N, lognk, t; bool headw;
    if (bid < 768)       { const int m = bid >> 8;
                           W = (m == 0) ? wq_m : (m == 1) ? wk_m : wv_m;
                           Wt = wt + (size_t)m * M_;
                           K = 1024; N = 1024; lognk = 4; headw = true;  t = bid & 255; }
    else if (bid < 1024) { W = proj_m_w; Wt = wt + 6 * M_;
                           K = 1024; N = 1024; lognk = 4; headw = false; t = bid - 768; }
    else if (bid < 1792) { const int m = (bid - 1024) >> 8;
                           W = (m == 0) ? wq_f : (m == 1) ? wk_f : wv_f;
                           Wt = wt + (size_t)(3 + m) * M_;
                           K = 1024; N = 1024; lognk = 4; headw = true;  t = (bid - 1024) & 255; }
    else if (bid < 2048) { W = proj_f_w; Wt = wt + 7 * M_;
                           K = 1024; N = 1024; lognk = 4; headw = false; t = bid - 1792; }
    else if (bid < 3072) { W = w1; Wt = wt + 8 * M_;
                           K = 1024; N = 4096; lognk = 4; headw = false; t = bid - 2048; }
    else                 { W = w2; Wt = wt + 12 * M_;
                           K = 4096; N = 1024; lognk = 6; headw = false; t = bid - 3072; }

    const int k0 = (t & ((1 << lognk) - 1)) * 64;
    const int n0 = (t >> lognk) * 64;

    #pragma unroll
    for (int r = 0; r < 4; ++r) {
        const int idx = tid + r * 256;
        const int kl  = idx >> 4;
        const int nl4 = (idx & 15) * 4;
        const float* gp;
        if (headw) {
            gp = W + ((size_t)(n0 >> 6) * K + (k0 + kl)) * 64 + nl4;
        } else {
            gp = W + (size_t)(k0 + kl) * N + n0 + nl4;
        }
        float4 v = *reinterpret_cast<const float4*>(gp);
        tt[kl][nl4 + 0] = v.x; tt[kl][nl4 + 1] = v.y;
        tt[kl][nl4 + 2] = v.z; tt[kl][nl4 + 3] = v.w;
    }
    __syncthreads();
    #pragma unroll
    for (int r = 0; r < 4; ++r) {
        const int idx = tid + r * 256;
        const int nl  = idx >> 4;
        const int kl4 = (idx & 15) * 4;
        half4 o;
        o.x = (f16)tt[kl4 + 0][nl];
        o.y = (f16)tt[kl4 + 1][nl];
        o.z = (f16)tt[kl4 + 2][nl];
        o.w = (f16)tt[kl4 + 3][nl];
        *reinterpret_cast<half4*>(&Wt[(size_t)(n0 + nl) * K + k0 + kl4]) = o;
    }
}

// ---------------- fp16 MFMA GEMM, BM x 128 tiles, BK=32, 2-buffer --------------
// Round-9 proven structure: stage(next) issued before compute(cur), one
// __syncthreads per K-step. Column-major block walk under the XCD swizzle.
// grid (N/128, M/BM, ksplit). PARTIAL: z writes f16 partials to outH + z*M*N.
// HEADOUT: col -> mat = col>>10, out = outH + mat*2M + head-layout index.
template<int BM, int EPI, bool HEADOUT, bool SPLITA, bool OHALF, bool PARTIAL>
__global__ __launch_bounds__(256, 2) void gemm_mfma(
    const f16* __restrict__ A1,
    const f16* __restrict__ A2,
    const f16* __restrict__ Bt,
    const float* __restrict__ bias,
    float* __restrict__ outF,
    f16* __restrict__ outH,
    int N, int K, int splitN)
{
    constexpr int BK = 32;
    constexpr int MI = 4;
    constexpr int NI = (BM == 128) ? 4 : 2;
    constexpr int WN = (BM == 128) ? 64 : 32;
    constexpr int ASLOT = BM * 4;
    constexpr int AINST = ASLOT / 256;

    __shared__ f16 ldsA[2][ASLOT * 8];
    __shared__ f16 ldsB[2][512 * 8];

    const int tid  = threadIdx.x;
    const int lane = tid & 63;
    const int wid  = tid >> 6;
    const int gy = gridDim.y;
    const int lin = xcd_swizzle(blockIdx.y * gridDim.x + blockIdx.x,
                                gridDim.x * gy);
    const int m0 = (lin % gy) * BM;
    const int n0 = (lin / gy) * 128;
    const int wm = (BM == 128) ? (wid >> 1) : 0;
    const int wn = (BM == 128) ? (wid & 1) : wid;

    const int Klen  = K / gridDim.z;
    const int kbase = blockIdx.z * Klen;

    const f16* Aptr = (SPLITA && n0 >= splitN) ? A2 : A1;

    f32x4 acc[MI][NI];
    #pragma unroll
    for (int i = 0; i < MI; ++i)
        #pragma unroll
        for (int j = 0; j < NI; ++j)
            acc[i][j] = (f32x4){0.f, 0.f, 0.f, 0.f};

    auto stage = [&](int buf, int kt) {
        const int k0 = kbase + kt * BK;
        #pragma unroll
        for (int i = 0; i < AINST; ++i) {
            const int s   = (wid * AINST + i) * 64 + lane;
            const int kh  = s / BM;
            const int row = s % BM;
            load_lds16(Aptr + (size_t)(m0 + row) * K + (k0 + kh * 8),
                       &ldsA[buf][s * 8]);
        }
        #pragma unroll
        for (int i = 0; i < 2; ++i) {
            const int s   = (wid * 2 + i) * 64 + lane;
            const int kh  = s >> 7;
            const int col = s & 127;
            load_lds16(Bt + (size_t)(n0 + col) * K + (k0 + kh * 8),
                       &ldsB[buf][s * 8]);
        }
    };

    const int NT = Klen / BK;
    stage(0, 0);
    __syncthreads();
    int cur = 0;
    const int l15 = lane & 15, l4 = lane >> 4;
    for (int kt = 0; kt < NT; ++kt) {
        if (kt + 1 < NT) stage(cur ^ 1, kt + 1);
        half8 af[MI], bfr[NI];
        #pragma unroll
        for (int mi = 0; mi < MI; ++mi)
            af[mi] = *reinterpret_cast<const half8*>(
                &ldsA[cur][(l4 * BM + wm * 64 + mi * 16 + l15) * 8]);
        #pragma unroll
        for (int ni = 0; ni < NI; ++ni)
            bfr[ni] = *reinterpret_cast<const half8*>(
                &ldsB[cur][(l4 * 128 + wn * WN + ni * 16 + l15) * 8]);
        #pragma unroll
        for (int mi = 0; mi < MI; ++mi)
            #pragma unroll
            for (int ni = 0; ni < NI; ++ni)
                acc[mi][ni] = __builtin_amdgcn_mfma_f32_16x16x32_f16(
                    af[mi], bfr[ni], acc[mi][ni], 0, 0, 0);
        __syncthreads();
        cur ^= 1;
    }

    f16* pout = nullptr;
    if (PARTIAL) {
        const size_t MN = (size_t)gridDim.y * BM * N;
        pout = outH + (size_t)blockIdx.z * MN;
    }

    #pragma unroll
    for (int mi = 0; mi < MI; ++mi) {
        #pragma unroll
        for (int ni = 0; ni < NI; ++ni) {
            #pragma unroll
            for (int r = 0; r < 4; ++r) {
                const int row = m0 + wm * 64 + mi * 16 + l4 * 4 + r;
                const int col = n0 + wn * WN + ni * 16 + l15;
                float v = acc[mi][ni][r];
                if (PARTIAL) {
                    pout[(size_t)row * N + col] = (f16)v;
                    continue;
                }
                if (EPI >= 1) v += bias[col];
                if (EPI == 2) v = 0.5f * v * (1.0f + erff(v * 0.70710678118f));
                size_t oidx;
                if (HEADOUT) {
                    const int mat = col >> 10;
                    const int h = (col >> 6) & 15, e = col & 63;
                    const int b = row >> 10, t = row & (TT - 1);
                    oidx = (size_t)mat * ((size_t)NROWS * DD)
                         + ((size_t)((b * HH + h) * TT + t)) * HS + e;
                } else {
                    oidx = (size_t)row * N + col;
                }
                if (OHALF) outH[oidx] = (f16)v;
                else       outF[oidx] = v;
            }
        }
    }
}

// ---------------- split-K reduce epilogues (f16 partials), N=1024, 1 row/block --
// MODE 0: out_h = sum4 + bias + residF(src)                  [m_out f16]
// MODE 1: outF = sum4 + bias + residH(m_out); xn = rms(outF) [f_out + fused rms]
// MODE 2: outF = sum4 + bias + residF(f_out)                 [final output]
template<int MODE>
__global__ __launch_bounds__(256) void reduce_fuse(const f16* __restrict__ part,
                                                   const float* __restrict__ bias,
                                                   const float* __restrict__ residF,
                                                   const f16* __restrict__ residH,
                                                   float* __restrict__ outF,
                                                   f16* __restrict__ outH,
                                                   const float* __restrict__ normw,
                                                   f16* __restrict__ xnout) {
    const size_t MN  = (size_t)NROWS * 1024;
    const int tid = threadIdx.x;
    const size_t idx = ((size_t)blockIdx.x * 256 + tid) * 4;
    float o[4];
    {
        half4 p0 = *reinterpret_cast<const half4*>(part + idx);
        half4 p1 = *reinterpret_cast<const half4*>(part + MN + idx);
        half4 p2 = *reinterpret_cast<const half4*>(part + 2 * MN + idx);
        half4 p3 = *reinterpret_cast<const half4*>(part + 3 * MN + idx);
        float4 bi = *reinterpret_cast<const float4*>(bias + (idx & 1023));
        o[0] = (float)p0.x + (float)p1.x + (float)p2.x + (float)p3.x + bi.x;
        o[1] = (float)p0.y + (float)p1.y + (float)p2.y + (float)p3.y + bi.y;
        o[2] = (float)p0.z + (float)p1.z + (float)p2.z + (float)p3.z + bi.z;
        o[3] = (float)p0.w + (float)p1.w + (float)p2.w + (float)p3.w + bi.w;
    }
    if (MODE == 0 || MODE == 2) {
        float4 rs = *reinterpret_cast<const float4*>(residF + idx);
        o[0] += rs.x; o[1] += rs.y; o[2] += rs.z; o[3] += rs.w;
    } else {
        half4 rh = *reinterpret_cast<const half4*>(residH + idx);
        o[0] += (float)rh.x; o[1] += (float)rh.y; o[2] += (float)rh.z; o[3] += (float)rh.w;
    }

    if (MODE == 0) {
        half4 h;
        h.x = (f16)o[0]; h.y = (f16)o[1]; h.z = (f16)o[2]; h.w = (f16)o[3];
        *reinterpret_cast<half4*>(outH + idx) = h;
        return;
    }

    float4 ov = {o[0], o[1], o[2], o[3]};
    *reinterpret_cast<float4*>(outF + idx) = ov;

    if (MODE == 1) {   // fused rmsnorm of the row (block == one row of 1024)
        __shared__ float red[256];
        red[tid] = o[0]*o[0] + o[1]*o[1] + o[2]*o[2] + o[3]*o[3];
        __syncthreads();
        for (int s = 128; s > 0; s >>= 1) {
            if (tid < s) red[tid] += red[tid + s];
            __syncthreads();
        }
        const float inv = rsqrtf(red[0] * (1.0f / DD) + EPS);
        float4 nw = *reinterpret_cast<const float4*>(normw + (idx & 1023));
        half4 h;
        h.x = (f16)(o[0] * inv * nw.x);
        h.y = (f16)(o[1] * inv * nw.y);
        h.z = (f16)(o[2] * inv * nw.z);
        h.w = (f16)(o[3] * inv * nw.w);
        *reinterpret_cast<half4*>(xnout + idx) = h;
    }
}

// ---------------- v_f split-K(2) reduce + bias + head-layout scatter ------------
__global__ __launch_bounds__(256) void reduce_vf(const f16* __restrict__ part,
                                                 const float* __restrict__ bv,
                                                 f16* __restrict__ out) {
    const size_t MN = (size_t)NROWS * 1024;
    const int t   = blockIdx.x;            // 0..2047
    const int tid = threadIdx.x;
    const int n   = tid * 4;               // col 0..1023
    const size_t idx = (size_t)t * 1024 + n;
    half4 p0 = *reinterpret_cast<const half4*>(part + idx);
    half4 p1 = *reinterpret_cast<const half4*>(part + MN + idx);
    float4 bi = *reinterpret_cast<const float4*>(bv + n);
    half4 o;
    o.x = (f16)((float)p0.x + (float)p1.x + bi.x);
    o.y = (f16)((float)p0.y + (float)p1.y + bi.y);
    o.z = (f16)((float)p0.z + (float)p1.z + bi.z);
    o.w = (f16)((float)p0.w + (float)p1.w + bi.w);
    const int b = t >> 10, tl = t & (TT - 1);
    const int h = n >> 6, e = n & (HS - 1);
    *reinterpret_cast<half4*>(
        &out[((size_t)(b * HH + h) * TT + tl) * HS + e]) = o;
}

// ---------------- MFMA flash attention (fp16 in/out, fp32 softmax/acc) ----------------
// Double-buffered K/V staging, stage-before-compute (GEMM pattern + T14):
// per tile: issue async K gll + V reg-loads for NEXT tile -> QK^T MFMA (hides
// load latency) -> softmax -> V pack/ds_write to other buffer -> PV -> 1 barrier.
// CAUSAL: complementary iq remap balances triangular tile counts across CUs.
template<bool CAUSAL>
__global__ __launch_bounds__(256) void attn_mfma(const f16* __restrict__ Q,
                                                 const f16* __restrict__ Kg,
                                                 const f16* __restrict__ Vg,
                                                 f16* __restrict__ O) {
    int iq, bh;
    if (CAUSAL) {
        bh = blockIdx.y;
        iq = (blockIdx.y < 16) ? blockIdx.x : (15 - blockIdx.x);
    } else {
        iq = blockIdx.x; bh = blockIdx.y;
    }
    const int tid = threadIdx.x;
    const int lane = tid & 63;
    const int w   = tid >> 6;
    const int l15 = lane & 15, l4 = lane >> 4;

    __shared__ f16 Ks[2][512 * 8];   // slot-major: slot = eh*64 + s
    __shared__ f16 VT[2][64 * 72];   // VT[e][s], row stride 72
    __shared__ f16 Ps[4][16 * 72];   // per-wave P[q'][s], row stride 72

    const f16* qb = Q  + ((size_t)bh * TT + (size_t)iq * 64) * HS;
    const f16* kb = Kg + (size_t)bh * TT * HS;
    const f16* vb = Vg + (size_t)bh * TT * HS;

    half8 qf[2];
    #pragma unroll
    for (int ks = 0; ks < 2; ++ks)
        qf[ks] = *reinterpret_cast<const half8*>(
            qb + (size_t)(w * 16 + l15) * HS + ks * 32 + l4 * 8);

    f32x4 oacc[4];
    #pragma unroll
    for (int ni = 0; ni < 4; ++ni) oacc[ni] = (f32x4){0.f, 0.f, 0.f, 0.f};
    float m_run[4], l_run[4];
    #pragma unroll
    for (int r = 0; r < 4; ++r) { m_run[r] = -1e30f; l_run[r] = 0.f; }

    const int sp  = lane & 31;
    const int ehv = lane >> 5;
    const int c0  = w * 16 + ehv * 8;

    auto stageK = [&](int buf, int js) {
        #pragma unroll
        for (int i = 0; i < 2; ++i) {
            const int slot = (w * 2 + i) * 64 + lane;
            load_lds16(kb + (size_t)(js * 64 + (slot & 63)) * HS + (slot >> 6) * 8,
                       &Ks[buf][slot * 8]);
        }
    };
    auto loadV = [&](int js, uint4& r0, uint4& r1) {
        const f16* vrow = vb + (size_t)(js * 64 + 2 * sp) * HS + c0;
        r0 = *reinterpret_cast<const uint4*>(vrow);
        r1 = *reinterpret_cast<const uint4*>(vrow + HS);
    };
    auto packV = [&](int buf, const uint4& r0, const uint4& r1) {
        const unsigned rc0[4] = {r0.x, r0.y, r0.z, r0.w};
        const unsigned rc1[4] = {r1.x, r1.y, r1.z, r1.w};
        #pragma unroll
        for (int i = 0; i < 8; ++i) {
            const unsigned lo = (i & 1) ? (rc0[i >> 1] >> 16) : (rc0[i >> 1] & 0xffffu);
            const unsigned hi = (i & 1) ? (rc1[i >> 1] >> 16) : (rc1[i >> 1] & 0xffffu);
            *reinterpret_cast<unsigned*>(&VT[buf][(c0 + i) * 72 + 2 * sp]) = lo | (hi << 16);
        }
    };

    const int ntiles = CAUSAL ? (iq + 1) : (TT / 64);

    // prologue: stage tile 0 into buffer 0
    {
        uint4 v0, v1;
        stageK(0, 0);
        loadV(0, v0, v1);
        packV(0, v0, v1);
    }
    __syncthreads();

    int cur = 0;
    for (int js = 0; js < ntiles; ++js) {
        const bool has_next = (js + 1 < ntiles);
        uint4 v0, v1;
        if (has_next) {
            stageK(cur ^ 1, js + 1);   // async gll, in flight across compute
            loadV(js + 1, v0, v1);     // reg loads; wait deferred to packV
        }

        // S = Q . K^T  (from Ks[cur])
        f32x4 sacc[4];
        #pragma unroll
        for (int ni = 0; ni < 4; ++ni) sacc[ni] = (f32x4){0.f, 0.f, 0.f, 0.f};
        __builtin_amdgcn_s_setprio(1);
        #pragma unroll
        for (int ks = 0; ks < 2; ++ks) {
            #pragma unroll
            for (int ni = 0; ni < 4; ++ni) {
                half8 kf = *reinterpret_cast<const half8*>(
                    &Ks[cur][((ks * 4 + l4) * 64 + ni * 16 + l15) * 8]);
                sacc[ni] = __builtin_amdgcn_mfma_f32_16x16x32_f16(qf[ks], kf, sacc[ni], 0, 0, 0);
            }
        }
        __builtin_amdgcn_s_setprio(0);

        float sv[4][4];
        #pragma unroll
        for (int ni = 0; ni < 4; ++ni) {
            #pragma unroll
            for (int r = 0; r < 4; ++r) {
                float x = sacc[ni][r] * SCALE;
                if (CAUSAL && js == iq) {
                    const int sg = js * 64 + ni * 16 + l15;
                    const int qg = iq * 64 + w * 16 + l4 * 4 + r;
                    if (sg > qg) x = -1e30f;
                }
                sv[ni][r] = x;
            }
        }

        #pragma unroll
        for (int r = 0; r < 4; ++r) {
            float rm = fmaxf(fmaxf(sv[0][r], sv[1][r]), fmaxf(sv[2][r], sv[3][r]));
            rm = fmaxf(rm, __shfl_xor(rm, 1));
            rm = fmaxf(rm, __shfl_xor(rm, 2));
            rm = fmaxf(rm, __shfl_xor(rm, 4));
            rm = fmaxf(rm, __shfl_xor(rm, 8));
            const float mnew = fmaxf(m_run[r], rm);
            const float corr = __expf(m_run[r] - mnew);
            float p0 = __expf(sv[0][r] - mnew);
            float p1 = __expf(sv[1][r] - mnew);
            float p2 = __expf(sv[2][r] - mnew);
            float p3 = __expf(sv[3][r] - mnew);
            float sum = p0 + p1 + p2 + p3;
            sum += __shfl_xor(sum, 1);
            sum += __shfl_xor(sum, 2);
            sum += __shfl_xor(sum, 4);
            sum += __shfl_xor(sum, 8);
            l_run[r] = l_run[r] * corr + sum;
            m_run[r] = mnew;
            #pragma unroll
            for (int ni = 0; ni < 4; ++ni) oacc[ni][r] *= corr;
            f16* prow = &Ps[w][(l4 * 4 + r) * 72];
            prow[ 0 + l15] = (f16)p0;
            prow[16 + l15] = (f16)p1;
            prow[32 + l15] = (f16)p2;
            prow[48 + l15] = (f16)p3;
        }

        // write-late: V regs have been in flight across QK^T + softmax
        if (has_next) packV(cur ^ 1, v0, v1);

        // O += P . V  (from VT[cur])
        __builtin_amdgcn_s_setprio(1);
        #pragma unroll
        for (int ks = 0; ks < 2; ++ks) {
            half8 pf = *reinterpret_cast<const half8*>(&Ps[w][l15 * 72 + ks * 32 + l4 * 8]);
            #pragma unroll
            for (int ni = 0; ni < 4; ++ni) {
                half8 vf = *reinterpret_cast<const half8*>(
                    &VT[cur][(ni * 16 + l15) * 72 + ks * 32 + l4 * 8]);
                oacc[ni] = __builtin_amdgcn_mfma_f32_16x16x32_f16(pf, vf, oacc[ni], 0, 0, 0);
            }
        }
        __builtin_amdgcn_s_setprio(0);

        __syncthreads();   // all waves done reading Ks[cur]/VT[cur]; stage drained
        cur ^= 1;
    }

    const int b = bh >> 4, h = bh & (HH - 1);
    #pragma unroll
    for (int r = 0; r < 4; ++r) {
        const float inv = 1.0f / l_run[r];
        const int t = iq * 64 + w * 16 + l4 * 4 + r;
        #pragma unroll
        for (int ni = 0; ni < 4; ++ni)
            O[((size_t)(b * TT + t)) * DD + h * HS + ni * 16 + l15] =
                (f16)(oacc[ni][r] * inv);
    }
}

extern "C" void kernel_launch(void* const* d_in, const int* in_sizes, int n_in,
                              void* d_out, int out_size, void* d_ws, size_t ws_size,
                              hipStream_t stream) {
    const float* src      = (const float*)d_in[0];
    const float* att      = (const float*)d_in[1];
    const float* wq_m     = (const float*)d_in[2];
    const float* wk_m     = (const float*)d_in[3];
    const float* wv_m     = (const float*)d_in[4];
    const float* proj_m_w = (const float*)d_in[5];
    const float* proj_m_b = (const float*)d_in[6];
    const float* wq_f     = (const float*)d_in[7];
    const float* wk_f     = (const float*)d_in[8];
    const float* wv_f     = (const float*)d_in[9];
    const float* bq_f     = (const float*)d_in[10];
    const float* bk_f     = (const float*)d_in[11];
    const float* bv_f     = (const float*)d_in[12];
    const float* proj_f_w = (const float*)d_in[13];
    const float* proj_f_b = (const float*)d_in[14];
    const float* w1       = (const float*)d_in[15];
    const float* b1       = (const float*)d_in[16];
    const float* w2       = (const float*)d_in[17];
    const float* b2       = (const float*)d_in[18];
    const float* norm_w   = (const float*)d_in[19];

    const size_t M_ = 1024 * 1024;
    f16* wsb = (f16*)d_ws;
    // ws layout (f16 units), peak 46M f16 = 92MB (proven OK):
    f16* wt      = wsb;                  //  0..16M  weights
    f16* headbuf = wsb + 16 * M_;        // 16..28M  q_m,k_m,v_m,q_f,k_f,v_f (2M each)
    f16* h1      = wsb + 16 * M_;        // 16..24M  FFN hidden (overlays headbuf)
    f16* xn_s    = wsb + 28 * M_;        // 28..30M  rms(src)
    f16* xn_a    = wsb + 30 * M_;        // 30..32M  rms(att)
    f16* ao      = wsb + 32 * M_;        // 32..34M  attn out
    f16* mo_h    = wsb + 34 * M_;        // 34..36M  m_out (f16)
    f16* partH   = wsb + 36 * M_;        // 36..44M  up to 4 x [2048][1024] f16
    f16* xn2     = wsb + 44 * M_;        // 44..46M  rms(f_out) = FFN input
    // d_out scratch before final write:
    float* biascat = (float*)d_out;                    // 5120 floats
    float* f_out = (float*)d_out;
    float* outp  = (float*)d_out;
    (void)ws_size; (void)in_sizes; (void)n_in;

    const dim3 blk(256);
    const int BIG = 1 << 30;
    const dim3 gQKV(40, 16);       // N=5120, BM=128 -> 640 blocks
    const dim3 gVF(8, 32, 2);      // N=1024, BM=64, K split 2 -> 512 blocks
    const dim3 gW1(32, 16);        // N=4096, BM=128 -> 512 blocks (direct GELU)
    const dim3 gSPLIT(8, 16, 4);   // N=1024, BM=128, K split 4 -> 512 blocks
    const dim3 gRED(2048);

    // ---- fused prologue: weights + bias pack + both rmsnorms ----
    prologue_all<<<dim3(8193), blk, 0, stream>>>(
        wq_m, wk_m, wv_m, proj_m_w, wq_f, wk_f, wv_f, proj_f_w, w1, w2,
        wt, bq_f, bk_f, biascat, src, att, norm_w, xn_s, xn_a);

    // ---- merged QKV_m + Q_f/K_f GEMM: N=5120, cols>=3072 read xn_a ----
    gemm_mfma<128, 1, true, true, true, false><<<gQKV, blk, 0, stream>>>(
        xn_s, xn_a, wt, biascat, nullptr, headbuf, 5120, 1024, 3072);

    // ---- masked self-attention block ----
    attn_mfma<true><<<dim3(16, 32), blk, 0, stream>>>(
        headbuf, headbuf + 2 * M_, headbuf + 4 * M_, ao);
    gemm_mfma<128, 0, false, false, false, true><<<gSPLIT, blk, 0, stream>>>(
        ao, nullptr, wt + 6 * M_, nullptr, nullptr, partH, 1024, 1024, BIG);
    reduce_fuse<0><<<gRED, blk, 0, stream>>>(
        partH, proj_m_b, src, nullptr, nullptr, mo_h, nullptr, nullptr);

    // ---- cross attention block: v_f from m_out (split-K2 + head-scatter reduce) --
    gemm_mfma<64, 0, false, false, false, true><<<gVF, blk, 0, stream>>>(
        mo_h, nullptr, wt + 5 * M_, nullptr, nullptr, partH, 1024, 1024, BIG);
    reduce_vf<<<dim3(NROWS), blk, 0, stream>>>(partH, bv_f, headbuf + 10 * M_);
    attn_mfma<false><<<dim3(16, 32), blk, 0, stream>>>(
        headbuf + 6 * M_, headbuf + 8 * M_, headbuf + 10 * M_, ao);
    gemm_mfma<128, 0, false, false, false, true><<<gSPLIT, blk, 0, stream>>>(
        ao, nullptr, wt + 7 * M_, nullptr, nullptr, partH, 1024, 1024, BIG);
    reduce_fuse<1><<<gRED, blk, 0, stream>>>(
        partH, proj_f_b, nullptr, mo_h, f_out, nullptr, norm_w, xn2);

    // ---- FFN block: w1 direct (bias+GELU fused) -> w2 split-K(4) ----
    gemm_mfma<128, 2, false, false, true, false><<<gW1, blk, 0, stream>>>(
        xn2, nullptr, wt + 8 * M_, b1, nullptr, h1, 4096, 1024, BIG);
    gemm_mfma<128, 0, false, false, false, true><<<gSPLIT, blk, 0, stream>>>(
        h1, nullptr, wt + 12 * M_, nullptr, nullptr, partH, 1024, 4096, BIG);
    reduce_fuse<2><<<gRED, blk, 0, stream>>>(
        partH, b2, f_out, nullptr, outp, nullptr, nullptr, nullptr);
}

// Round 18
// 294.466 us; speedup vs baseline: 1.0858x; 1.0006x over previous
//
#include <hip/hip_runtime.h>
#include <math.h>

#define BB 2
#define TT 1024
#define DD 1024
#define HH 16
#define HS 64
#define NROWS (BB*TT)   // 2048

typedef _Float16 f16;
typedef __attribute__((ext_vector_type(8))) _Float16 half8;
typedef __attribute__((ext_vector_type(4))) _Float16 half4;
typedef __attribute__((ext_vector_type(4))) float f32x4;

constexpr float EPS   = 1e-5f;
constexpr float SCALE = 8.0f;   // faithful bug: scores * sqrt(HS)

__device__ __forceinline__ void load_lds16(const f16* g, f16* l) {
    __builtin_amdgcn_global_load_lds(
        (const __attribute__((address_space(1))) unsigned int*)g,
        (__attribute__((address_space(3))) unsigned int*)l, 16, 0, 0);
}

// XCD-aware bijective swizzle of the linear block id (total % 8 == 0).
__device__ __forceinline__ int xcd_swizzle(int lin, int total) {
    if ((total & 7) == 0) {
        const int chunk = total >> 3;
        lin = (lin & 7) * chunk + (lin >> 3);
    }
    return lin;
}

// ---------------- fused prologue: 10 weight transposes + bias pack + 2 rmsnorms --
// blocks 0..4095: transpose tiles; 4096: bias pack; 4097..8192: rmsnorm rows
// (0..2047 = src -> xn_s, 2048..4095 = att -> xn_a).
// wt layout (f16, units of M_=1M): [0:3 qkv_m][3 wq_f][4 wk_f][5 wv_f][6 projm]
//                                  [7 projf][8:12 w1][12:16 w2]
__global__ __launch_bounds__(256) void prologue_all(
    const float* __restrict__ wq_m, const float* __restrict__ wk_m,
    const float* __restrict__ wv_m, const float* __restrict__ proj_m_w,
    const float* __restrict__ wq_f, const float* __restrict__ wk_f,
    const float* __restrict__ wv_f, const float* __restrict__ proj_f_w,
    const float* __restrict__ w1,   const float* __restrict__ w2,
    f16* __restrict__ wt,
    const float* __restrict__ bq, const float* __restrict__ bk,
    float* __restrict__ biascat,
    const float* __restrict__ src, const float* __restrict__ att,
    const float* __restrict__ normw,
    f16* __restrict__ xn_s, f16* __restrict__ xn_a)
{
    const int bid = blockIdx.x;
    const int tid = threadIdx.x;
    const size_t M_ = 1024 * 1024;

    __shared__ float tt[64][65];

    if (bid == 4096) {   // bias pack: [0]*3072 | bq | bk  (5120 floats)
        for (int j = tid; j < 5120; j += 256)
            biascat[j] = (j < 3072) ? 0.f : ((j < 4096) ? bq[j - 3072] : bk[j - 4096]);
        return;
    }

    if (bid > 4096) {    // rmsnorm row
        const int rrow = bid - 4097;            // 0..4095
        const int row  = rrow & (NROWS - 1);
        const float* xr = ((rrow < NROWS) ? src : att) + (size_t)row * DD;
        f16* out = ((rrow < NROWS) ? xn_s : xn_a) + (size_t)row * DD;

        float4 xv = reinterpret_cast<const float4*>(xr)[tid];
        float ss = xv.x*xv.x + xv.y*xv.y + xv.z*xv.z + xv.w*xv.w;
        float* red = &tt[0][0];
        red[tid] = ss; __syncthreads();
        for (int s = 128; s > 0; s >>= 1) {
            if (tid < s) red[tid] += red[tid + s];
            __syncthreads();
        }
        const float inv = rsqrtf(red[0] * (1.0f / DD) + EPS);
        float4 wv = reinterpret_cast<const float4*>(normw)[tid];
        half4 o;
        o.x = (f16)(xv.x * inv * wv.x);
        o.y = (f16)(xv.y * inv * wv.y);
        o.z = (f16)(xv.z * inv * wv.z);
        o.w = (f16)(xv.w * inv * wv.w);
        *reinterpret_cast<half4*>(&out[tid * 4]) = o;
        return;
    }

    // weight transpose tile
    const float* W; f16* Wt; int K, N, lognk, t; bool headw;
    if (bid < 768)       { const int m = bid >> 8;
                           W = (m == 0) ? wq_m : (m == 1) ? wk_m : wv_m;
                           Wt = wt + (size_t)m * M_;
                           K = 1024; N = 1024; lognk = 4; headw = true;  t = bid & 255; }
    else if (bid < 1024) { W = proj_m_w; Wt = wt + 6 * M_;
                           K = 1024; N = 1024; lognk = 4; headw = false; t = bid - 768; }
    else if (bid < 1792) { const int m = (bid - 1024) >> 8;
                           W = (m == 0) ? wq_f : (m == 1) ? wk_f : wv_f;
                           Wt = wt + (size_t)(3 + m) * M_;
                           K = 1024; N = 1024; lognk = 4; headw = true;  t = (bid - 1024) & 255; }
    else if (bid < 2048) { W = proj_f_w; Wt = wt + 7 * M_;
                           K = 1024; N = 1024; lognk = 4; headw = false; t = bid - 1792; }
    else if (bid < 3072) { W = w1; Wt = wt + 8 * M_;
                           K = 1024; N = 4096; lognk = 4; headw = false; t = bid - 2048; }
    else                 { W = w2; Wt = wt + 12 * M_;
                           K = 4096; N = 1024; lognk = 6; headw = false; t = bid - 3072; }

    const int k0 = (t & ((1 << lognk) - 1)) * 64;
    const int n0 = (t >> lognk) * 64;

    #pragma unroll
    for (int r = 0; r < 4; ++r) {
        const int idx = tid + r * 256;
        const int kl  = idx >> 4;
        const int nl4 = (idx & 15) * 4;
        const float* gp;
        if (headw) {
            gp = W + ((size_t)(n0 >> 6) * K + (k0 + kl)) * 64 + nl4;
        } else {
            gp = W + (size_t)(k0 + kl) * N + n0 + nl4;
        }
        float4 v = *reinterpret_cast<const float4*>(gp);
        tt[kl][nl4 + 0] = v.x; tt[kl][nl4 + 1] = v.y;
        tt[kl][nl4 + 2] = v.z; tt[kl][nl4 + 3] = v.w;
    }
    __syncthreads();
    #pragma unroll
    for (int r = 0; r < 4; ++r) {
        const int idx = tid + r * 256;
        const int nl  = idx >> 4;
        const int kl4 = (idx & 15) * 4;
        half4 o;
        o.x = (f16)tt[kl4 + 0][nl];
        o.y = (f16)tt[kl4 + 1][nl];
        o.z = (f16)tt[kl4 + 2][nl];
        o.w = (f16)tt[kl4 + 3][nl];
        *reinterpret_cast<half4*>(&Wt[(size_t)(n0 + nl) * K + k0 + kl4]) = o;
    }
}

// ---------------- fp16 MFMA GEMM, BM x 128 tiles, BK=32, 2-buffer --------------
// Round-9 proven structure: stage(next) issued before compute(cur), one
// __syncthreads per K-step. Column-major block walk under the XCD swizzle.
// grid (N/128, M/BM, ksplit). PARTIAL: z writes f16 partials to outH + z*M*N.
// HEADOUT: col -> mat = col>>10, out = outH + mat*2M + head-layout index.
template<int BM, int EPI, bool HEADOUT, bool SPLITA, bool OHALF, bool PARTIAL>
__global__ __launch_bounds__(256, 2) void gemm_mfma(
    const f16* __restrict__ A1,
    const f16* __restrict__ A2,
    const f16* __restrict__ Bt,
    const float* __restrict__ bias,
    float* __restrict__ outF,
    f16* __restrict__ outH,
    int N, int K, int splitN)
{
    constexpr int BK = 32;
    constexpr int MI = 4;
    constexpr int NI = (BM == 128) ? 4 : 2;
    constexpr int WN = (BM == 128) ? 64 : 32;
    constexpr int ASLOT = BM * 4;
    constexpr int AINST = ASLOT / 256;

    __shared__ f16 ldsA[2][ASLOT * 8];
    __shared__ f16 ldsB[2][512 * 8];

    const int tid  = threadIdx.x;
    const int lane = tid & 63;
    const int wid  = tid >> 6;
    const int gy = gridDim.y;
    const int lin = xcd_swizzle(blockIdx.y * gridDim.x + blockIdx.x,
                                gridDim.x * gy);
    const int m0 = (lin % gy) * BM;
    const int n0 = (lin / gy) * 128;
    const int wm = (BM == 128) ? (wid >> 1) : 0;
    const int wn = (BM == 128) ? (wid & 1) : wid;

    const int Klen  = K / gridDim.z;
    const int kbase = blockIdx.z * Klen;

    const f16* Aptr = (SPLITA && n0 >= splitN) ? A2 : A1;

    f32x4 acc[MI][NI];
    #pragma unroll
    for (int i = 0; i < MI; ++i)
        #pragma unroll
        for (int j = 0; j < NI; ++j)
            acc[i][j] = (f32x4){0.f, 0.f, 0.f, 0.f};

    auto stage = [&](int buf, int kt) {
        const int k0 = kbase + kt * BK;
        #pragma unroll
        for (int i = 0; i < AINST; ++i) {
            const int s   = (wid * AINST + i) * 64 + lane;
            const int kh  = s / BM;
            const int row = s % BM;
            load_lds16(Aptr + (size_t)(m0 + row) * K + (k0 + kh * 8),
                       &ldsA[buf][s * 8]);
        }
        #pragma unroll
        for (int i = 0; i < 2; ++i) {
            const int s   = (wid * 2 + i) * 64 + lane;
            const int kh  = s >> 7;
            const int col = s & 127;
            load_lds16(Bt + (size_t)(n0 + col) * K + (k0 + kh * 8),
                       &ldsB[buf][s * 8]);
        }
    };

    const int NT = Klen / BK;
    stage(0, 0);
    __syncthreads();
    int cur = 0;
    const int l15 = lane & 15, l4 = lane >> 4;
    for (int kt = 0; kt < NT; ++kt) {
        if (kt + 1 < NT) stage(cur ^ 1, kt + 1);
        half8 af[MI], bfr[NI];
        #pragma unroll
        for (int mi = 0; mi < MI; ++mi)
            af[mi] = *reinterpret_cast<const half8*>(
                &ldsA[cur][(l4 * BM + wm * 64 + mi * 16 + l15) * 8]);
        #pragma unroll
        for (int ni = 0; ni < NI; ++ni)
            bfr[ni] = *reinterpret_cast<const half8*>(
                &ldsB[cur][(l4 * 128 + wn * WN + ni * 16 + l15) * 8]);
        #pragma unroll
        for (int mi = 0; mi < MI; ++mi)
            #pragma unroll
            for (int ni = 0; ni < NI; ++ni)
                acc[mi][ni] = __builtin_amdgcn_mfma_f32_16x16x32_f16(
                    af[mi], bfr[ni], acc[mi][ni], 0, 0, 0);
        __syncthreads();
        cur ^= 1;
    }

    f16* pout = nullptr;
    if (PARTIAL) {
        const size_t MN = (size_t)gridDim.y * BM * N;
        pout = outH + (size_t)blockIdx.z * MN;
    }

    #pragma unroll
    for (int mi = 0; mi < MI; ++mi) {
        #pragma unroll
        for (int ni = 0; ni < NI; ++ni) {
            #pragma unroll
            for (int r = 0; r < 4; ++r) {
                const int row = m0 + wm * 64 + mi * 16 + l4 * 4 + r;
                const int col = n0 + wn * WN + ni * 16 + l15;
                float v = acc[mi][ni][r];
                if (PARTIAL) {
                    pout[(size_t)row * N + col] = (f16)v;
                    continue;
                }
                if (EPI >= 1) v += bias[col];
                if (EPI == 2) v = 0.5f * v * (1.0f + erff(v * 0.70710678118f));
                size_t oidx;
                if (HEADOUT) {
                    const int mat = col >> 10;
                    const int h = (col >> 6) & 15, e = col & 63;
                    const int b = row >> 10, t = row & (TT - 1);
                    oidx = (size_t)mat * ((size_t)NROWS * DD)
                         + ((size_t)((b * HH + h) * TT + t)) * HS + e;
                } else {
                    oidx = (size_t)row * N + col;
                }
                if (OHALF) outH[oidx] = (f16)v;
                else       outF[oidx] = v;
            }
        }
    }
}

// ---------------- split-K reduce epilogues (f16 partials), N=1024, 1 row/block --
// MODE 0: out_h = sum4 + bias + residF(src)                  [m_out f16]
// MODE 1: outF = sum4 + bias + residH(m_out); xn = rms(outF) [f_out + fused rms]
// MODE 2: outF = sum4 + bias + residF(f_out)                 [final output]
template<int MODE>
__global__ __launch_bounds__(256) void reduce_fuse(const f16* __restrict__ part,
                                                   const float* __restrict__ bias,
                                                   const float* __restrict__ residF,
                                                   const f16* __restrict__ residH,
                                                   float* __restrict__ outF,
                                                   f16* __restrict__ outH,
                                                   const float* __restrict__ normw,
                                                   f16* __restrict__ xnout) {
    const size_t MN  = (size_t)NROWS * 1024;
    const int tid = threadIdx.x;
    const size_t idx = ((size_t)blockIdx.x * 256 + tid) * 4;
    float o[4];
    {
        half4 p0 = *reinterpret_cast<const half4*>(part + idx);
        half4 p1 = *reinterpret_cast<const half4*>(part + MN + idx);
        half4 p2 = *reinterpret_cast<const half4*>(part + 2 * MN + idx);
        half4 p3 = *reinterpret_cast<const half4*>(part + 3 * MN + idx);
        float4 bi = *reinterpret_cast<const float4*>(bias + (idx & 1023));
        o[0] = (float)p0.x + (float)p1.x + (float)p2.x + (float)p3.x + bi.x;
        o[1] = (float)p0.y + (float)p1.y + (float)p2.y + (float)p3.y + bi.y;
        o[2] = (float)p0.z + (float)p1.z + (float)p2.z + (float)p3.z + bi.z;
        o[3] = (float)p0.w + (float)p1.w + (float)p2.w + (float)p3.w + bi.w;
    }
    if (MODE == 0 || MODE == 2) {
        float4 rs = *reinterpret_cast<const float4*>(residF + idx);
        o[0] += rs.x; o[1] += rs.y; o[2] += rs.z; o[3] += rs.w;
    } else {
        half4 rh = *reinterpret_cast<const half4*>(residH + idx);
        o[0] += (float)rh.x; o[1] += (float)rh.y; o[2] += (float)rh.z; o[3] += (float)rh.w;
    }

    if (MODE == 0) {
        half4 h;
        h.x = (f16)o[0]; h.y = (f16)o[1]; h.z = (f16)o[2]; h.w = (f16)o[3];
        *reinterpret_cast<half4*>(outH + idx) = h;
        return;
    }

    float4 ov = {o[0], o[1], o[2], o[3]};
    *reinterpret_cast<float4*>(outF + idx) = ov;

    if (MODE == 1) {   // fused rmsnorm of the row (block == one row of 1024)
        __shared__ float red[256];
        red[tid] = o[0]*o[0] + o[1]*o[1] + o[2]*o[2] + o[3]*o[3];
        __syncthreads();
        for (int s = 128; s > 0; s >>= 1) {
            if (tid < s) red[tid] += red[tid + s];
            __syncthreads();
        }
        const float inv = rsqrtf(red[0] * (1.0f / DD) + EPS);
        float4 nw = *reinterpret_cast<const float4*>(normw + (idx & 1023));
        half4 h;
        h.x = (f16)(o[0] * inv * nw.x);
        h.y = (f16)(o[1] * inv * nw.y);
        h.z = (f16)(o[2] * inv * nw.z);
        h.w = (f16)(o[3] * inv * nw.w);
        *reinterpret_cast<half4*>(xnout + idx) = h;
    }
}

// ---------------- v_f split-K(2) reduce + bias + head-layout scatter ------------
__global__ __launch_bounds__(256) void reduce_vf(const f16* __restrict__ part,
                                                 const float* __restrict__ bv,
                                                 f16* __restrict__ out) {
    const size_t MN = (size_t)NROWS * 1024;
    const int t   = blockIdx.x;            // 0..2047
    const int tid = threadIdx.x;
    const int n   = tid * 4;               // col 0..1023
    const size_t idx = (size_t)t * 1024 + n;
    half4 p0 = *reinterpret_cast<const half4*>(part + idx);
    half4 p1 = *reinterpret_cast<const half4*>(part + MN + idx);
    float4 bi = *reinterpret_cast<const float4*>(bv + n);
    half4 o;
    o.x = (f16)((float)p0.x + (float)p1.x + bi.x);
    o.y = (f16)((float)p0.y + (float)p1.y + bi.y);
    o.z = (f16)((float)p0.z + (float)p1.z + bi.z);
    o.w = (f16)((float)p0.w + (float)p1.w + bi.w);
    const int b = t >> 10, tl = t & (TT - 1);
    const int h = n >> 6, e = n & (HS - 1);
    *reinterpret_cast<half4*>(
        &out[((size_t)(b * HH + h) * TT + tl) * HS + e]) = o;
}

// ---------------- MFMA flash attention (fp16 in/out, fp32 softmax/acc) ----------------
// Double-buffered K/V staging, stage-before-compute (GEMM pattern + T14):
// per tile: issue async K gll + V reg-loads for NEXT tile -> QK^T MFMA (hides
// load latency) -> softmax -> V pack/ds_write to other buffer -> PV -> 1 barrier.
// CAUSAL: complementary iq remap balances triangular tile counts across CUs.
template<bool CAUSAL>
__global__ __launch_bounds__(256) void attn_mfma(const f16* __restrict__ Q,
                                                 const f16* __restrict__ Kg,
                                                 const f16* __restrict__ Vg,
                                                 f16* __restrict__ O) {
    int iq, bh;
    if (CAUSAL) {
        bh = blockIdx.y;
        iq = (blockIdx.y < 16) ? blockIdx.x : (15 - blockIdx.x);
    } else {
        iq = blockIdx.x; bh = blockIdx.y;
    }
    const int tid = threadIdx.x;
    const int lane = tid & 63;
    const int w   = tid >> 6;
    const int l15 = lane & 15, l4 = lane >> 4;

    __shared__ f16 Ks[2][512 * 8];   // slot-major: slot = eh*64 + s
    __shared__ f16 VT[2][64 * 72];   // VT[e][s], row stride 72
    __shared__ f16 Ps[4][16 * 72];   // per-wave P[q'][s], row stride 72

    const f16* qb = Q  + ((size_t)bh * TT + (size_t)iq * 64) * HS;
    const f16* kb = Kg + (size_t)bh * TT * HS;
    const f16* vb = Vg + (size_t)bh * TT * HS;

    half8 qf[2];
    #pragma unroll
    for (int ks = 0; ks < 2; ++ks)
        qf[ks] = *reinterpret_cast<const half8*>(
            qb + (size_t)(w * 16 + l15) * HS + ks * 32 + l4 * 8);

    f32x4 oacc[4];
    #pragma unroll
    for (int ni = 0; ni < 4; ++ni) oacc[ni] = (f32x4){0.f, 0.f, 0.f, 0.f};
    float m_run[4], l_run[4];
    #pragma unroll
    for (int r = 0; r < 4; ++r) { m_run[r] = -1e30f; l_run[r] = 0.f; }

    const int sp  = lane & 31;
    const int ehv = lane >> 5;
    const int c0  = w * 16 + ehv * 8;

    auto stageK = [&](int buf, int js) {
        #pragma unroll
        for (int i = 0; i < 2; ++i) {
            const int slot = (w * 2 + i) * 64 + lane;
            load_lds16(kb + (size_t)(js * 64 + (slot & 63)) * HS + (slot >> 6) * 8,
                       &Ks[buf][slot * 8]);
        }
    };
    auto loadV = [&](int js, uint4& r0, uint4& r1) {
        const f16* vrow = vb + (size_t)(js * 64 + 2 * sp) * HS + c0;
        r0 = *reinterpret_cast<const uint4*>(vrow);
        r1 = *reinterpret_cast<const uint4*>(vrow + HS);
    };
    auto packV = [&](int buf, const uint4& r0, const uint4& r1) {
        const unsigned rc0[4] = {r0.x, r0.y, r0.z, r0.w};
        const unsigned rc1[4] = {r1.x, r1.y, r1.z, r1.w};
        #pragma unroll
        for (int i = 0; i < 8; ++i) {
            const unsigned lo = (i & 1) ? (rc0[i >> 1] >> 16) : (rc0[i >> 1] & 0xffffu);
            const unsigned hi = (i & 1) ? (rc1[i >> 1] >> 16) : (rc1[i >> 1] & 0xffffu);
            *reinterpret_cast<unsigned*>(&VT[buf][(c0 + i) * 72 + 2 * sp]) = lo | (hi << 16);
        }
    };

    const int ntiles = CAUSAL ? (iq + 1) : (TT / 64);

    // prologue: stage tile 0 into buffer 0
    {
        uint4 v0, v1;
        stageK(0, 0);
        loadV(0, v0, v1);
        packV(0, v0, v1);
    }
    __syncthreads();

    int cur = 0;
    for (int js = 0; js < ntiles; ++js) {
        const bool has_next = (js + 1 < ntiles);
        uint4 v0, v1;
        if (has_next) {
            stageK(cur ^ 1, js + 1);   // async gll, in flight across compute
            loadV(js + 1, v0, v1);     // reg loads; wait deferred to packV
        }

        // S = Q . K^T  (from Ks[cur])
        f32x4 sacc[4];
        #pragma unroll
        for (int ni = 0; ni < 4; ++ni) sacc[ni] = (f32x4){0.f, 0.f, 0.f, 0.f};
        __builtin_amdgcn_s_setprio(1);
        #pragma unroll
        for (int ks = 0; ks < 2; ++ks) {
            #pragma unroll
            for (int ni = 0; ni < 4; ++ni) {
                half8 kf = *reinterpret_cast<const half8*>(
                    &Ks[cur][((ks * 4 + l4) * 64 + ni * 16 + l15) * 8]);
                sacc[ni] = __builtin_amdgcn_mfma_f32_16x16x32_f16(qf[ks], kf, sacc[ni], 0, 0, 0);
            }
        }
        __builtin_amdgcn_s_setprio(0);

        float sv[4][4];
        #pragma unroll
        for (int ni = 0; ni < 4; ++ni) {
            #pragma unroll
            for (int r = 0; r < 4; ++r) {
                float x = sacc[ni][r] * SCALE;
                if (CAUSAL && js == iq) {
                    const int sg = js * 64 + ni * 16 + l15;
                    const int qg = iq * 64 + w * 16 + l4 * 4 + r;
                    if (sg > qg) x = -1e30f;
                }
                sv[ni][r] = x;
            }
        }

        #pragma unroll
        for (int r = 0; r < 4; ++r) {
            float rm = fmaxf(fmaxf(sv[0][r], sv[1][r]), fmaxf(sv[2][r], sv[3][r]));
            rm = fmaxf(rm, __shfl_xor(rm, 1));
            rm = fmaxf(rm, __shfl_xor(rm, 2));
            rm = fmaxf(rm, __shfl_xor(rm, 4));
            rm = fmaxf(rm, __shfl_xor(rm, 8));
            const float mnew = fmaxf(m_run[r], rm);
            const float corr = __expf(m_run[r] - mnew);
            float p0 = __expf(sv[0][r] - mnew);
            float p1 = __expf(sv[1][r] - mnew);
            float p2 = __expf(sv[2][r] - mnew);
            float p3 = __expf(sv[3][r] - mnew);
            float sum = p0 + p1 + p2 + p3;
            sum += __shfl_xor(sum, 1);
            sum += __shfl_xor(sum, 2);
            sum += __shfl_xor(sum, 4);
            sum += __shfl_xor(sum, 8);
            l_run[r] = l_run[r] * corr + sum;
            m_run[r] = mnew;
            #pragma unroll
            for (int ni = 0; ni < 4; ++ni) oacc[ni][r] *= corr;
            f16* prow = &Ps[w][(l4 * 4 + r) * 72];
            prow[ 0 + l15] = (f16)p0;
            prow[16 + l15] = (f16)p1;
            prow[32 + l15] = (f16)p2;
            prow[48 + l15] = (f16)p3;
        }

        // write-late: V regs have been in flight across QK^T + softmax
        if (has_next) packV(cur ^ 1, v0, v1);

        // O += P . V  (from VT[cur])
        __builtin_amdgcn_s_setprio(1);
        #pragma unroll
        for (int ks = 0; ks < 2; ++ks) {
            half8 pf = *reinterpret_cast<const half8*>(&Ps[w][l15 * 72 + ks * 32 + l4 * 8]);
            #pragma unroll
            for (int ni = 0; ni < 4; ++ni) {
                half8 vf = *reinterpret_cast<const half8*>(
                    &VT[cur][(ni * 16 + l15) * 72 + ks * 32 + l4 * 8]);
                oacc[ni] = __builtin_amdgcn_mfma_f32_16x16x32_f16(pf, vf, oacc[ni], 0, 0, 0);
            }
        }
        __builtin_amdgcn_s_setprio(0);

        __syncthreads();   // all waves done reading Ks[cur]/VT[cur]; stage drained
        cur ^= 1;
    }

    const int b = bh >> 4, h = bh & (HH - 1);
    #pragma unroll
    for (int r = 0; r < 4; ++r) {
        const float inv = 1.0f / l_run[r];
        const int t = iq * 64 + w * 16 + l4 * 4 + r;
        #pragma unroll
        for (int ni = 0; ni < 4; ++ni)
            O[((size_t)(b * TT + t)) * DD + h * HS + ni * 16 + l15] =
                (f16)(oacc[ni][r] * inv);
    }
}

extern "C" void kernel_launch(void* const* d_in, const int* in_sizes, int n_in,
                              void* d_out, int out_size, void* d_ws, size_t ws_size,
                              hipStream_t stream) {
    const float* src      = (const float*)d_in[0];
    const float* att      = (const float*)d_in[1];
    const float* wq_m     = (const float*)d_in[2];
    const float* wk_m     = (const float*)d_in[3];
    const float* wv_m     = (const float*)d_in[4];
    const float* proj_m_w = (const float*)d_in[5];
    const float* proj_m_b = (const float*)d_in[6];
    const float* wq_f     = (const float*)d_in[7];
    const float* wk_f     = (const float*)d_in[8];
    const float* wv_f     = (const float*)d_in[9];
    const float* bq_f     = (const float*)d_in[10];
    const float* bk_f     = (const float*)d_in[11];
    const float* bv_f     = (const float*)d_in[12];
    const float* proj_f_w = (const float*)d_in[13];
    const float* proj_f_b = (const float*)d_in[14];
    const float* w1       = (const float*)d_in[15];
    const float* b1       = (const float*)d_in[16];
    const float* w2       = (const float*)d_in[17];
    const float* b2       = (const float*)d_in[18];
    const float* norm_w   = (const float*)d_in[19];

    const size_t M_ = 1024 * 1024;
    f16* wsb = (f16*)d_ws;
    // ws layout (f16 units), peak 46M f16 = 92MB (proven OK):
    f16* wt      = wsb;                  //  0..16M  weights
    f16* headbuf = wsb + 16 * M_;        // 16..28M  q_m,k_m,v_m,q_f,k_f,v_f (2M each)
    f16* h1      = wsb + 16 * M_;        // 16..24M  FFN hidden (overlays headbuf)
    f16* xn_s    = wsb + 28 * M_;        // 28..30M  rms(src)
    f16* xn_a    = wsb + 30 * M_;        // 30..32M  rms(att)
    f16* ao      = wsb + 32 * M_;        // 32..34M  attn out
    f16* mo_h    = wsb + 34 * M_;        // 34..36M  m_out (f16)
    f16* partH   = wsb + 36 * M_;        // 36..44M  up to 4 x [2048][1024] f16
    f16* xn2     = wsb + 44 * M_;        // 44..46M  rms(f_out) = FFN input
    // d_out scratch before final write:
    float* biascat = (float*)d_out;                    // 5120 floats
    float* f_out = (float*)d_out;
    float* outp  = (float*)d_out;
    (void)ws_size; (void)in_sizes; (void)n_in;

    const dim3 blk(256);
    const int BIG = 1 << 30;
    const dim3 gQKV(40, 16);       // N=5120, BM=128 -> 640 blocks
    const dim3 gVF(8, 32, 2);      // N=1024, BM=64, K split 2 -> 512 blocks
    const dim3 gW1(32, 16);        // N=4096, BM=128 -> 512 blocks (direct GELU)
    const dim3 gSPLIT(8, 16, 4);   // N=1024, BM=128, K split 4 -> 512 blocks
    const dim3 gRED(2048);

    // ---- fused prologue: weights + bias pack + both rmsnorms ----
    prologue_all<<<dim3(8193), blk, 0, stream>>>(
        wq_m, wk_m, wv_m, proj_m_w, wq_f, wk_f, wv_f, proj_f_w, w1, w2,
        wt, bq_f, bk_f, biascat, src, att, norm_w, xn_s, xn_a);

    // ---- merged QKV_m + Q_f/K_f GEMM: N=5120, cols>=3072 read xn_a ----
    gemm_mfma<128, 1, true, true, true, false><<<gQKV, blk, 0, stream>>>(
        xn_s, xn_a, wt, biascat, nullptr, headbuf, 5120, 1024, 3072);

    // ---- masked self-attention block ----
    attn_mfma<true><<<dim3(16, 32), blk, 0, stream>>>(
        headbuf, headbuf + 2 * M_, headbuf + 4 * M_, ao);
    gemm_mfma<128, 0, false, false, false, true><<<gSPLIT, blk, 0, stream>>>(
        ao, nullptr, wt + 6 * M_, nullptr, nullptr, partH, 1024, 1024, BIG);
    reduce_fuse<0><<<gRED, blk, 0, stream>>>(
        partH, proj_m_b, src, nullptr, nullptr, mo_h, nullptr, nullptr);

    // ---- cross attention block: v_f from m_out (split-K2 + head-scatter reduce) --
    gemm_mfma<64, 0, false, false, false, true><<<gVF, blk, 0, stream>>>(
        mo_h, nullptr, wt + 5 * M_, nullptr, nullptr, partH, 1024, 1024, BIG);
    reduce_vf<<<dim3(NROWS), blk, 0, stream>>>(partH, bv_f, headbuf + 10 * M_);
    attn_mfma<false><<<dim3(16, 32), blk, 0, stream>>>(
        headbuf + 6 * M_, headbuf + 8 * M_, headbuf + 10 * M_, ao);
    gemm_mfma<128, 0, false, false, false, true><<<gSPLIT, blk, 0, stream>>>(
        ao, nullptr, wt + 7 * M_, nullptr, nullptr, partH, 1024, 1024, BIG);
    reduce_fuse<1><<<gRED, blk, 0, stream>>>(
        partH, proj_f_b, nullptr, mo_h, f_out, nullptr, norm_w, xn2);

    // ---- FFN block: w1 direct (bias+GELU fused) -> w2 split-K(4) ----
    gemm_mfma<128, 2, false, false, true, false><<<gW1, blk, 0, stream>>>(
        xn2, nullptr, wt + 8 * M_, b1, nullptr, h1, 4096, 1024, BIG);
    gemm_mfma<128, 0, false, false, false, true><<<gSPLIT, blk, 0, stream>>>(
        h1, nullptr, wt + 12 * M_, nullptr, nullptr, partH, 1024, 4096, BIG);
    reduce_fuse<2><<<gRED, blk, 0, stream>>>(
        partH, b2, f_out, nullptr, outp, nullptr, nullptr, nullptr);
}